// Round 4
// baseline (285.076 us; speedup 1.0000x reference)
//
#include <hip/hip_runtime.h>
#include <cstdint>
#include <cstddef>

typedef unsigned short u16;
typedef __attribute__((ext_vector_type(8))) short short8;
typedef __attribute__((ext_vector_type(4))) float f32x4;
typedef __attribute__((ext_vector_type(4))) float float4v;
typedef __attribute__((ext_vector_type(4))) u16 u16x4;

__device__ __forceinline__ u16 f2bf(float f) {
  union { float f; uint32_t u; } v; v.f = f;
  uint32_t u = v.u;
  return (u16)((u + 0x7FFFu + ((u >> 16) & 1u)) >> 16);
}
__device__ __forceinline__ float bf2f(u16 s) {
  union { uint32_t u; float f; } v; v.u = ((uint32_t)s) << 16; return v.f;
}

__device__ __forceinline__ float fast_exp2(float x) {
#if __has_builtin(__builtin_amdgcn_exp2f)
  return __builtin_amdgcn_exp2f(x);
#else
  return exp2f(x);
#endif
}

// async global->LDS, 16B per lane, dest = wave-uniform base + lane*16
__device__ __forceinline__ void gload16(const u16* g, u16* l) {
  __builtin_amdgcn_global_load_lds((const __attribute__((address_space(1))) void*)g,
                                   (__attribute__((address_space(3))) void*)l,
                                   16, 0, 0);
}

// ---------------- convert f32 -> bf16 ----------------
__global__ __launch_bounds__(256) void k_cvt(const float* __restrict__ in, u16* __restrict__ out, int n4) {
  int i = blockIdx.x * 256 + threadIdx.x;
  if (i >= n4) return;
  float4v v = *(const float4v*)(in + (size_t)i * 4);
  u16x4 o;
  #pragma unroll
  for (int j = 0; j < 4; j++) o[j] = f2bf(v[j]);
  *(u16x4*)(out + (size_t)i * 4) = o;
}

// ---------------- layernorm f32 -> bf16 (one block per row of 1024) ----------------
__global__ __launch_bounds__(256) void k_ln(const float* __restrict__ x, const float* __restrict__ g,
                                            const float* __restrict__ b, u16* __restrict__ out) {
  int row = blockIdx.x, tid = threadIdx.x;
  int wid = tid >> 6;
  const float* xr = x + (size_t)row * 1024;
  float4v v = *(const float4v*)(xr + tid * 4);
  float s = v[0] + v[1] + v[2] + v[3];
  float sq = v[0]*v[0] + v[1]*v[1] + v[2]*v[2] + v[3]*v[3];
  #pragma unroll
  for (int m = 1; m <= 32; m <<= 1) { s += __shfl_xor(s, m); sq += __shfl_xor(sq, m); }
  __shared__ float ss[4], ssq[4];
  if ((tid & 63) == 0) { ss[wid] = s; ssq[wid] = sq; }
  __syncthreads();
  s = ss[0] + ss[1] + ss[2] + ss[3];
  sq = ssq[0] + ssq[1] + ssq[2] + ssq[3];
  float mu = s * (1.0f/1024.0f);
  float var = sq * (1.0f/1024.0f) - mu*mu;
  float rs = rsqrtf(var + 1e-5f);
  u16x4 o;
  #pragma unroll
  for (int j = 0; j < 4; j++) {
    float y = (v[j] - mu) * rs * g[tid*4+j] + b[tid*4+j];
    o[j] = f2bf(y);
  }
  *(u16x4*)(out + (size_t)row * 1024 + tid * 4) = o;
}

// ---------------- GEMM: C[M,N] = A[M,K] @ B[N,K]^T  (bf16 in, fp32 acc) ----------------
// m97 shape: 256 thr / 4 waves (2x2), 128x128 tile, 64x64 per wave, BK=64,
// single 32KB LDS buffer, global_load_lds w=16 (linear dest, pre-swizzled source).
// Split-K via blockIdx.z (Ksub per chunk, K = full row stride).
// EPI: 2=bf16 gelu(acc+bias), 4=bf16 plain, 6=bf16 partial at z*M*N
template<int EPI>
__global__ __launch_bounds__(256) void k_gemm(const u16* __restrict__ A, const u16* __restrict__ B,
                                              const float* __restrict__ bias, u16* __restrict__ Cb,
                                              int M, int N, int K, int Ksub) {
  __shared__ __align__(16) u16 As[128*64];
  __shared__ __align__(16) u16 Bs[128*64];
  int tid = threadIdx.x;
  // bijective XCD-chunked swizzle on (x,y)
  int gx = gridDim.x;
  int lin = blockIdx.y * gx + blockIdx.x;
  int nwg = gx * gridDim.y;
  int cpx = nwg >> 3;
  int swz = (lin & 7) * cpx + (lin >> 3);
  int bx = swz % gx, by = swz / gx;
  int m0 = by * 128, n0 = bx * 128;
  int kbase = blockIdx.z * Ksub;
  int wid = tid >> 6, lane = tid & 63;
  int wr = wid >> 1, wc = wid & 1;          // wave tile: 64x64
  int l15 = lane & 15, l16 = lane >> 4;
  int gslot = (tid & 7) ^ ((tid >> 3) & 7); // inverse swizzle on global source
  int srow = tid >> 3;                      // + i*32

  f32x4 acc[4][4] = {};
  int nt = Ksub >> 6;

  for (int t = 0; t < nt; ++t) {
    int kb = kbase + (t << 6);
    #pragma unroll
    for (int i = 0; i < 4; i++) {
      int row = i*32 + srow;
      gload16(A + (size_t)(m0+row)*K + kb + gslot*8, &As[i*2048 + wid*512]);
      gload16(B + (size_t)(n0+row)*K + kb + gslot*8, &Bs[i*2048 + wid*512]);
    }
    __syncthreads();
    #pragma unroll
    for (int ks = 0; ks < 2; ks++) {
      short8 af[4], bfr[4];
      #pragma unroll
      for (int m = 0; m < 4; m++) {
        int row = wr*64 + m*16 + l15;
        af[m] = *(const short8*)&As[row*64 + (((ks*4 + l16) ^ (row & 7)) * 8)];
      }
      #pragma unroll
      for (int n = 0; n < 4; n++) {
        int row = wc*64 + n*16 + l15;
        bfr[n] = *(const short8*)&Bs[row*64 + (((ks*4 + l16) ^ (row & 7)) * 8)];
      }
      #pragma unroll
      for (int m = 0; m < 4; m++)
        #pragma unroll
        for (int n = 0; n < 4; n++)
          acc[m][n] = __builtin_amdgcn_mfma_f32_16x16x32_bf16(af[m], bfr[n], acc[m][n], 0, 0, 0);
    }
    __syncthreads();
  }

  size_t zoff = (EPI == 6) ? (size_t)blockIdx.z * M * N : 0;
  #pragma unroll
  for (int m = 0; m < 4; m++) {
    #pragma unroll
    for (int n = 0; n < 4; n++) {
      int col = n0 + wc*64 + n*16 + l15;
      #pragma unroll
      for (int r = 0; r < 4; r++) {
        int row = m0 + wr*64 + m*16 + l16*4 + r;
        float v = acc[m][n][r];
        if constexpr (EPI == 2) { v += bias[col]; v = 0.5f*v*(1.0f + erff(v*0.70710678118f)); }
        Cb[zoff + (size_t)row*N + col] = f2bf(v);
      }
    }
  }
}

// ---------------- reduce: x1 = x + P0 + P1  (P bf16 partials) ----------------
__global__ __launch_bounds__(256) void k_red2(const float* __restrict__ x, const u16* __restrict__ P,
                                              float* __restrict__ x1) {
  int i = blockIdx.x * 256 + threadIdx.x;     // float4 index, 1048576 total
  float4v v = *(const float4v*)(x + (size_t)i * 4);
  #pragma unroll
  for (int z = 0; z < 2; z++) {
    u16x4 p = *(const u16x4*)(P + (size_t)z * 4194304 + (size_t)i * 4);
    #pragma unroll
    for (int j = 0; j < 4; j++) v[j] += bf2f(p[j]);
  }
  *(float4v*)(x1 + (size_t)i * 4) = v;
}

// ---------------- reduce: out = x1 + b2 + Q0+Q1+Q2+Q3 ----------------
__global__ __launch_bounds__(256) void k_red4(const float* __restrict__ x1, const float* __restrict__ b2,
                                              const u16* __restrict__ Q, float* __restrict__ out) {
  int i = blockIdx.x * 256 + threadIdx.x;     // float4 index, 1048576 total
  float4v v = *(const float4v*)(x1 + (size_t)i * 4);
  float4v bb = *(const float4v*)(b2 + (size_t)(i & 255) * 4);
  #pragma unroll
  for (int j = 0; j < 4; j++) v[j] += bb[j];
  #pragma unroll
  for (int z = 0; z < 4; z++) {
    u16x4 p = *(const u16x4*)(Q + (size_t)z * 4194304 + (size_t)i * 4);
    #pragma unroll
    for (int j = 0; j < 4; j++) v[j] += bf2f(p[j]);
  }
  *(float4v*)(out + (size_t)i * 4) = v;
}

// ---------------- prep: l2norm q,k (fold temp*log2e into q), V -> V^T ----------------
__global__ __launch_bounds__(256) void k_prep(const u16* __restrict__ qkv, const float* __restrict__ temp,
                                              u16* __restrict__ Qn, u16* __restrict__ Kn, u16* __restrict__ Vt) {
  int grp = blockIdx.x, bh = blockIdx.y;
  int b = bh >> 4, h = bh & 15;
  int tid = threadIdx.x, wid = tid >> 6, lane = tid & 63;
  int n0 = grp * 64;
  __shared__ __align__(16) u16 vs[64*64];
  float tmp = temp[h] * 1.44269504f;   // fold log2e for exp2-domain softmax
  for (int j = 0; j < 16; j++) {
    int tl = wid + 4*j;
    size_t roff = (size_t)((b*2048) + n0 + tl) * 3072;
    float q = bf2f(qkv[roff + h*64 + lane]);
    float k = bf2f(qkv[roff + 1024 + h*64 + lane]);
    u16 vraw = qkv[roff + 2048 + h*64 + lane];
    float sq = q*q, sk = k*k;
    #pragma unroll
    for (int m = 1; m <= 32; m <<= 1) { sq += __shfl_xor(sq, m); sk += __shfl_xor(sk, m); }
    float qs = tmp / fmaxf(sqrtf(sq), 1e-12f);
    float ksc = 1.0f / fmaxf(sqrtf(sk), 1e-12f);
    size_t obase = ((size_t)bh*2048 + n0 + tl)*64 + lane;
    Qn[obase] = f2bf(q * qs);
    Kn[obase] = f2bf(k * ksc);
    vs[tl*64 + lane] = vraw;
  }
  __syncthreads();
  int d = tid & 63, chunk = tid >> 6;
  u16 vals[16];
  #pragma unroll
  for (int jj = 0; jj < 16; jj++) vals[jj] = vs[(chunk*16 + jj)*64 + d];
  short8 w0, w1v;
  #pragma unroll
  for (int j = 0; j < 8; j++) { w0[j] = (short)vals[j]; w1v[j] = (short)vals[8+j]; }
  size_t vo = ((size_t)bh*64 + d)*2048 + n0 + chunk*16;
  *(short8*)(Vt + vo) = w0;
  *(short8*)(Vt + vo + 8) = w1v;
}

// ---------------- flash attention, swapped-QK^T, fixed-max softmax, dbuf K/V ----------------
__global__ __launch_bounds__(256) void k_attn(const u16* __restrict__ Qn, const u16* __restrict__ Kn,
                                              const u16* __restrict__ Vt, const float* __restrict__ temp,
                                              u16* __restrict__ Out) {
  __shared__ __align__(16) u16 Ks[2][64*64];
  __shared__ __align__(16) u16 Vs[2][64*64];
  __shared__ __align__(16) u16 Ps[4*16*64];
  int qg = blockIdx.x, bh = blockIdx.y;
  int b = bh >> 4, h = bh & 15;
  int tid = threadIdx.x, wid = tid >> 6, lane = tid & 63;
  int l15 = lane & 15, l16 = lane >> 4;
  size_t base = (size_t)bh * 2048 * 64;
  size_t vbase = (size_t)bh * 64 * 2048;
  int q0 = qg*64 + wid*16;
  float m2 = fabsf(temp[h]) * 1.44269504f;
  short8 qf[2];
  #pragma unroll
  for (int ks = 0; ks < 2; ks++)
    qf[ks] = *(const short8*)(Qn + base + (size_t)(q0 + l15)*64 + ks*32 + l16*8);
  f32x4 o[4] = {};
  float lrow = 0.f;
  u16* Pw = Ps + wid*16*64;
  uint32_t* Pw32 = (uint32_t*)Pw;

  auto STAGE = [&](int bsel, int kv0) {
    #pragma unroll
    for (int i = 0; i < 2; i++) {
      int base_row = wid*16 + i*8;
      int row = base_row + (lane >> 3);
      int gslot = (lane & 7) ^ (row & 7);
      gload16(Kn + base + (size_t)(kv0 + row)*64 + gslot*8, &Ks[bsel][base_row*64]);
      gload16(Vt + vbase + (size_t)row*2048 + kv0 + gslot*8, &Vs[bsel][base_row*64]);
    }
  };

  STAGE(0, 0);
  __syncthreads();
  int cur = 0;
  for (int kv0 = 0; kv0 < 2048; kv0 += 64) {
    if (kv0 + 64 < 2048) STAGE(cur ^ 1, kv0 + 64);
    f32x4 s[4] = {};
    #pragma unroll
    for (int ks = 0; ks < 2; ks++) {
      short8 kf[4];
      #pragma unroll
      for (int nt = 0; nt < 4; nt++) {
        int row = nt*16 + l15;
        kf[nt] = *(const short8*)&Ks[cur][row*64 + (((ks*4 + l16) ^ (row&7))*8)];
      }
      #pragma unroll
      for (int nt = 0; nt < 4; nt++)
        s[nt] = __builtin_amdgcn_mfma_f32_16x16x32_bf16(kf[nt], qf[ks], s[nt], 0, 0, 0);
    }
    float tsum = 0.f;
    #pragma unroll
    for (int nt = 0; nt < 4; nt++) {
      #pragma unroll
      for (int rp = 0; rp < 2; rp++) {
        float p0 = fast_exp2(s[nt][2*rp]   - m2);
        float p1 = fast_exp2(s[nt][2*rp+1] - m2);
        tsum += p0 + p1;
        uint32_t pk;
        asm("v_cvt_pk_bf16_f32 %0, %1, %2" : "=v"(pk) : "v"(p0), "v"(p1));
        int w = nt*8 + l16*2 + rp;
        int slot = w >> 2;
        Pw32[l15*32 + ((slot ^ (l15 & 7))*4) + (w & 3)] = pk;
      }
    }
    lrow += tsum;
    asm volatile("s_waitcnt lgkmcnt(0)" ::: "memory");
    __builtin_amdgcn_sched_barrier(0);
    #pragma unroll
    for (int ks = 0; ks < 2; ks++) {
      short8 pf = *(const short8*)&Pw[l15*64 + (((ks*4 + l16) ^ (l15&7))*8)];
      short8 vf[4];
      #pragma unroll
      for (int dt = 0; dt < 4; dt++) {
        int row = dt*16 + l15;
        vf[dt] = *(const short8*)&Vs[cur][row*64 + (((ks*4 + l16) ^ (row&7))*8)];
      }
      #pragma unroll
      for (int dt = 0; dt < 4; dt++)
        o[dt] = __builtin_amdgcn_mfma_f32_16x16x32_bf16(vf[dt], pf, o[dt], 0, 0, 0);
    }
    __syncthreads();
    cur ^= 1;
  }
  lrow += __shfl_xor(lrow, 16);
  lrow += __shfl_xor(lrow, 32);
  float rl = 1.0f / lrow;
  int tok = b*2048 + q0 + l15;
  #pragma unroll
  for (int dt = 0; dt < 4; dt++) {
    u16x4 ov;
    #pragma unroll
    for (int r = 0; r < 4; r++) ov[r] = f2bf(o[dt][r] * rl);
    *(u16x4*)(Out + (size_t)tok*1024 + h*64 + dt*16 + l16*4) = ov;
  }
}

// ---------------- workspace layout (bytes) ----------------
static constexpr size_t OFF_WQKV  = 0;                         // 3072*1024*2
static constexpr size_t OFF_WPROJ = OFF_WQKV  + 6291456;       // 1024*1024*2
static constexpr size_t OFF_W1    = OFF_WPROJ + 2097152;       // 4096*1024*2
static constexpr size_t OFF_W2    = OFF_W1    + 8388608;       // 1024*4096*2
static constexpr size_t OFF_HBF   = OFF_W2    + 8388608;       // 4096*1024*2
static constexpr size_t OFF_H2BF  = OFF_HBF   + 8388608;
static constexpr size_t OFF_QKVBF = OFF_H2BF  + 8388608;       // 4096*3072*2
static constexpr size_t OFF_QN    = OFF_QKVBF + 25165824;      // 32*2048*64*2
static constexpr size_t OFF_KN    = OFF_QN    + 8388608;
static constexpr size_t OFF_VT    = OFF_KN    + 8388608;
static constexpr size_t OFF_AOUT  = OFF_VT    + 8388608;
static constexpr size_t OFF_X1    = OFF_AOUT  + 8388608;       // 4096*1024*4
static constexpr size_t OFF_HID   = OFF_X1    + 16777216;      // 4096*4096*2
// partials reuse dead regions: proj P (16MB) at OFF_QN (Qn/Kn dead after attn);
// mlp2 Q (32MB) at OFF_QN..OFF_AOUT+8MB (all dead after proj)
static constexpr size_t OFF_P     = OFF_QN;

extern "C" void kernel_launch(void* const* d_in, const int* in_sizes, int n_in,
                              void* d_out, int out_size, void* d_ws, size_t ws_size,
                              hipStream_t stream) {
  (void)in_sizes; (void)n_in; (void)out_size; (void)ws_size;
  const float* x     = (const float*)d_in[0];
  const float* ln1g  = (const float*)d_in[1];
  const float* ln1b  = (const float*)d_in[2];
  const float* wqkv  = (const float*)d_in[3];
  const float* wproj = (const float*)d_in[4];
  const float* temp  = (const float*)d_in[5];
  const float* ln2g  = (const float*)d_in[6];
  const float* ln2b  = (const float*)d_in[7];
  const float* w1    = (const float*)d_in[8];
  const float* b1    = (const float*)d_in[9];
  const float* w2    = (const float*)d_in[10];
  const float* b2    = (const float*)d_in[11];

  char* ws = (char*)d_ws;
  u16* wqkv_bf  = (u16*)(ws + OFF_WQKV);
  u16* wproj_bf = (u16*)(ws + OFF_WPROJ);
  u16* w1_bf    = (u16*)(ws + OFF_W1);
  u16* w2_bf    = (u16*)(ws + OFF_W2);
  u16* h_bf     = (u16*)(ws + OFF_HBF);
  u16* h2_bf    = (u16*)(ws + OFF_H2BF);
  u16* qkv_bf   = (u16*)(ws + OFF_QKVBF);
  u16* Qn       = (u16*)(ws + OFF_QN);
  u16* Kn       = (u16*)(ws + OFF_KN);
  u16* Vt       = (u16*)(ws + OFF_VT);
  u16* aout_bf  = (u16*)(ws + OFF_AOUT);
  float* x1     = (float*)(ws + OFF_X1);
  u16* hid_bf   = (u16*)(ws + OFF_HID);
  u16* part     = (u16*)(ws + OFF_P);
  float* outf   = (float*)d_out;

  k_cvt<<<3072, 256, 0, stream>>>(wqkv,  wqkv_bf,  786432);
  k_cvt<<<1024, 256, 0, stream>>>(wproj, wproj_bf, 262144);
  k_cvt<<<4096, 256, 0, stream>>>(w1,    w1_bf,    1048576);
  k_cvt<<<4096, 256, 0, stream>>>(w2,    w2_bf,    1048576);

  k_ln<<<4096, 256, 0, stream>>>(x, ln1g, ln1b, h_bf);
  // qkv = h @ w_qkv^T -> bf16 [4096,3072]
  k_gemm<4><<<dim3(24, 32), 256, 0, stream>>>(h_bf, wqkv_bf, nullptr, qkv_bf, 4096, 3072, 1024, 1024);
  k_prep<<<dim3(32, 32), 256, 0, stream>>>(qkv_bf, temp, Qn, Kn, Vt);
  k_attn<<<dim3(32, 32), 256, 0, stream>>>(Qn, Kn, Vt, temp, aout_bf);
  // proj split-K=2: partials -> reduce x1 = x + P0 + P1
  k_gemm<6><<<dim3(8, 32, 2), 256, 0, stream>>>(aout_bf, wproj_bf, nullptr, part, 4096, 1024, 1024, 512);
  k_red2<<<4096, 256, 0, stream>>>(x, part, x1);
  k_ln<<<4096, 256, 0, stream>>>(x1, ln2g, ln2b, h2_bf);
  // mlp1: hid = gelu(h2 @ w1^T + b1) -> bf16 [4096,4096]
  k_gemm<2><<<dim3(32, 32), 256, 0, stream>>>(h2_bf, w1_bf, b1, hid_bf, 4096, 4096, 1024, 1024);
  // mlp2 split-K=4: partials -> reduce out = x1 + b2 + sum(Q)
  k_gemm<6><<<dim3(8, 32, 4), 256, 0, stream>>>(hid_bf, w2_bf, nullptr, part, 4096, 1024, 4096, 1024);
  k_red4<<<4096, 256, 0, stream>>>(x1, b2, part, outf);
}

// Round 5
// 268.523 us; speedup vs baseline: 1.0616x; 1.0616x over previous
//
#include <hip/hip_runtime.h>
#include <cstdint>
#include <cstddef>

typedef unsigned short u16;
typedef __attribute__((ext_vector_type(8))) short short8;
typedef __attribute__((ext_vector_type(4))) float f32x4;
typedef __attribute__((ext_vector_type(4))) float float4v;
typedef __attribute__((ext_vector_type(4))) u16 u16x4;

__device__ __forceinline__ u16 f2bf(float f) {
  union { float f; uint32_t u; } v; v.f = f;
  uint32_t u = v.u;
  return (u16)((u + 0x7FFFu + ((u >> 16) & 1u)) >> 16);
}
__device__ __forceinline__ float bf2f(u16 s) {
  union { uint32_t u; float f; } v; v.u = ((uint32_t)s) << 16; return v.f;
}

__device__ __forceinline__ float fast_exp2(float x) {
#if __has_builtin(__builtin_amdgcn_exp2f)
  return __builtin_amdgcn_exp2f(x);
#else
  return exp2f(x);
#endif
}

// async global->LDS, 16B per lane, dest = wave-uniform base + lane*16
__device__ __forceinline__ void gload16(const u16* g, u16* l) {
  __builtin_amdgcn_global_load_lds((const __attribute__((address_space(1))) void*)g,
                                   (__attribute__((address_space(3))) void*)l,
                                   16, 0, 0);
}

// ---------------- convert f32 -> bf16 ----------------
__global__ __launch_bounds__(256) void k_cvt(const float* __restrict__ in, u16* __restrict__ out, int n4) {
  int i = blockIdx.x * 256 + threadIdx.x;
  if (i >= n4) return;
  float4v v = *(const float4v*)(in + (size_t)i * 4);
  u16x4 o;
  #pragma unroll
  for (int j = 0; j < 4; j++) o[j] = f2bf(v[j]);
  *(u16x4*)(out + (size_t)i * 4) = o;
}

// ---------------- layernorm f32 -> bf16 (one block per row of 1024) ----------------
__global__ __launch_bounds__(256) void k_ln(const float* __restrict__ x, const float* __restrict__ g,
                                            const float* __restrict__ b, u16* __restrict__ out) {
  int row = blockIdx.x, tid = threadIdx.x;
  int wid = tid >> 6;
  const float* xr = x + (size_t)row * 1024;
  float4v v = *(const float4v*)(xr + tid * 4);
  float s = v[0] + v[1] + v[2] + v[3];
  float sq = v[0]*v[0] + v[1]*v[1] + v[2]*v[2] + v[3]*v[3];
  #pragma unroll
  for (int m = 1; m <= 32; m <<= 1) { s += __shfl_xor(s, m); sq += __shfl_xor(sq, m); }
  __shared__ float ss[4], ssq[4];
  if ((tid & 63) == 0) { ss[wid] = s; ssq[wid] = sq; }
  __syncthreads();
  s = ss[0] + ss[1] + ss[2] + ss[3];
  sq = ssq[0] + ssq[1] + ssq[2] + ssq[3];
  float mu = s * (1.0f/1024.0f);
  float var = sq * (1.0f/1024.0f) - mu*mu;
  float rs = rsqrtf(var + 1e-5f);
  u16x4 o;
  #pragma unroll
  for (int j = 0; j < 4; j++) {
    float y = (v[j] - mu) * rs * g[tid*4+j] + b[tid*4+j];
    o[j] = f2bf(y);
  }
  *(u16x4*)(out + (size_t)row * 1024 + tid * 4) = o;
}

// ================= 256x256 GEMM, BK=32, 3-deep counted-vmcnt pipeline =================
// C[M,N] = A[M,K] @ B[N,K]^T, bf16 in, fp32 acc. 512 thr / 8 waves (2M x 4N),
// wave tile 128x64 (8x4 frags). LDS: 3 buffers x (A 16KB + B 16KB) = 96KB dynamic.
// Packed LDS layout: lds-row R (128B) holds matrix rows 2R,2R+1; slot s'=(r&1)*4+g
// stored at p = s' ^ (R&7). Staging: linear LDS dest, inverse-swizzled global source.
// Pipeline per iter: vmcnt(4) -> s_barrier -> stage t+2 -> 12 ds_read -> lgkmcnt(0)
// -> 32 MFMA (setprio). In-flight loads cross every barrier (T4).
// EPI: 2=bf16 gelu(acc+bias), 4=bf16 plain, 6=bf16 partial at z*M*N
template<int EPI>
__global__ __launch_bounds__(512, 2) void k_g256(const u16* __restrict__ A, const u16* __restrict__ B,
                                                 const float* __restrict__ bias, u16* __restrict__ Cb,
                                                 int M, int N, int K, int Ksub) {
  extern __shared__ __align__(16) u16 smem[];   // [3][2][8192]
  int tid = threadIdx.x;
  // bijective XCD-chunked swizzle on (x,y); z untouched
  int gx = gridDim.x;
  int lin = blockIdx.y * gx + blockIdx.x;
  int nwg = gx * gridDim.y;
  int cpx = nwg >> 3;
  int swz = (lin & 7) * cpx + (lin >> 3);
  int bx = swz % gx, by = swz / gx;
  int m0 = by * 256, n0 = bx * 256;
  int kbase = blockIdx.z * Ksub;
  int wid = tid >> 6, lane = tid & 63;
  int wm = wid >> 2, wn = wid & 3;          // 2x4 waves; wave tile 128x64
  int l15 = lane & 15, l16 = lane >> 4;

  f32x4 acc[8][4] = {};
  int nt = Ksub >> 5;

  auto STAGE = [&](int bsel, int kb) {
    u16* abase = smem + bsel * 16384;
    u16* bbase = abase + 8192;
    #pragma unroll
    for (int i = 0; i < 2; i++) {
      int c = i*512 + tid;
      int R = c >> 3, p = c & 7;
      int sp = p ^ (R & 7);
      int r = 2*R + (sp >> 2);
      int g = sp & 3;
      gload16(A + (size_t)(m0 + r)*K + kb + g*8, abase + c*8);
      gload16(B + (size_t)(n0 + r)*K + kb + g*8, bbase + c*8);
    }
  };

  // prologue: stage tiles 0,1 (8 vm-instr in flight)
  STAGE(0, kbase);
  STAGE(1, kbase + 32);

  for (int t = 0; t < nt; ++t) {
    // wait: tile t landed (allow tile t+1's 4 loads to stay in flight)
    if (t + 1 < nt) asm volatile("s_waitcnt vmcnt(4)" ::: "memory");
    else            asm volatile("s_waitcnt vmcnt(0)" ::: "memory");
    __builtin_amdgcn_sched_barrier(0);
    __builtin_amdgcn_s_barrier();           // all waves: tile t ready, buf (t+2)%3 free
    __builtin_amdgcn_sched_barrier(0);
    if (t + 2 < nt) STAGE((t + 2) % 3, kbase + (t + 2) * 32);
    const u16* ab = smem + (t % 3) * 16384;
    const u16* bb = ab + 8192;
    short8 af[8], bf[4];
    #pragma unroll
    for (int mf = 0; mf < 8; mf++) {
      int r = wm*128 + mf*16 + l15;
      int R = r >> 1;
      int sp = ((r & 1)*4 + l16) ^ (R & 7);
      af[mf] = *(const short8*)(ab + R*64 + sp*8);
    }
    #pragma unroll
    for (int nf = 0; nf < 4; nf++) {
      int r = wn*64 + nf*16 + l15;
      int R = r >> 1;
      int sp = ((r & 1)*4 + l16) ^ (R & 7);
      bf[nf] = *(const short8*)(bb + R*64 + sp*8);
    }
    asm volatile("s_waitcnt lgkmcnt(0)" ::: "memory");
    __builtin_amdgcn_sched_barrier(0);
    __builtin_amdgcn_s_setprio(1);
    #pragma unroll
    for (int mf = 0; mf < 8; mf++)
      #pragma unroll
      for (int nf = 0; nf < 4; nf++)
        acc[mf][nf] = __builtin_amdgcn_mfma_f32_16x16x32_bf16(af[mf], bf[nf], acc[mf][nf], 0, 0, 0);
    __builtin_amdgcn_s_setprio(0);
  }

  size_t zoff = (EPI == 6) ? (size_t)blockIdx.z * M * N : 0;
  #pragma unroll
  for (int mf = 0; mf < 8; mf++) {
    #pragma unroll
    for (int nf = 0; nf < 4; nf++) {
      int col = n0 + wn*64 + nf*16 + l15;
      #pragma unroll
      for (int r = 0; r < 4; r++) {
        int row = m0 + wm*128 + mf*16 + l16*4 + r;
        float v = acc[mf][nf][r];
        if constexpr (EPI == 2) { v += bias[col]; v = 0.5f*v*(1.0f + erff(v*0.70710678118f)); }
        Cb[zoff + (size_t)row*N + col] = f2bf(v);
      }
    }
  }
}

// ---------------- reduce: out = base (+bias) + P0+P1+P2+P3 ----------------
template<int HASB>
__global__ __launch_bounds__(256) void k_red4(const float* __restrict__ base, const float* __restrict__ bias,
                                              const u16* __restrict__ P, float* __restrict__ out) {
  int i = blockIdx.x * 256 + threadIdx.x;     // float4 index, 1048576 total
  float4v v = *(const float4v*)(base + (size_t)i * 4);
  if constexpr (HASB) {
    float4v bb = *(const float4v*)(bias + (size_t)(i & 255) * 4);
    #pragma unroll
    for (int j = 0; j < 4; j++) v[j] += bb[j];
  }
  #pragma unroll
  for (int z = 0; z < 4; z++) {
    u16x4 p = *(const u16x4*)(P + (size_t)z * 4194304 + (size_t)i * 4);
    #pragma unroll
    for (int j = 0; j < 4; j++) v[j] += bf2f(p[j]);
  }
  *(float4v*)(out + (size_t)i * 4) = v;
}

// ---------------- prep: l2norm q,k (fold temp*log2e into q), V -> V^T ----------------
__global__ __launch_bounds__(256) void k_prep(const u16* __restrict__ qkv, const float* __restrict__ temp,
                                              u16* __restrict__ Qn, u16* __restrict__ Kn, u16* __restrict__ Vt) {
  int grp = blockIdx.x, bh = blockIdx.y;
  int b = bh >> 4, h = bh & 15;
  int tid = threadIdx.x, wid = tid >> 6, lane = tid & 63;
  int n0 = grp * 64;
  __shared__ __align__(16) u16 vs[64*64];
  float tmp = temp[h] * 1.44269504f;   // fold log2e for exp2-domain softmax
  for (int j = 0; j < 16; j++) {
    int tl = wid + 4*j;
    size_t roff = (size_t)((b*2048) + n0 + tl) * 3072;
    float q = bf2f(qkv[roff + h*64 + lane]);
    float k = bf2f(qkv[roff + 1024 + h*64 + lane]);
    u16 vraw = qkv[roff + 2048 + h*64 + lane];
    float sq = q*q, sk = k*k;
    #pragma unroll
    for (int m = 1; m <= 32; m <<= 1) { sq += __shfl_xor(sq, m); sk += __shfl_xor(sk, m); }
    float qs = tmp / fmaxf(sqrtf(sq), 1e-12f);
    float ksc = 1.0f / fmaxf(sqrtf(sk), 1e-12f);
    size_t obase = ((size_t)bh*2048 + n0 + tl)*64 + lane;
    Qn[obase] = f2bf(q * qs);
    Kn[obase] = f2bf(k * ksc);
    vs[tl*64 + lane] = vraw;
  }
  __syncthreads();
  int d = tid & 63, chunk = tid >> 6;
  u16 vals[16];
  #pragma unroll
  for (int jj = 0; jj < 16; jj++) vals[jj] = vs[(chunk*16 + jj)*64 + d];
  short8 w0, w1v;
  #pragma unroll
  for (int j = 0; j < 8; j++) { w0[j] = (short)vals[j]; w1v[j] = (short)vals[8+j]; }
  size_t vo = ((size_t)bh*64 + d)*2048 + n0 + chunk*16;
  *(short8*)(Vt + vo) = w0;
  *(short8*)(Vt + vo + 8) = w1v;
}

// ---------------- flash attention, swapped-QK^T, fixed-max softmax, dbuf K/V ----------------
__global__ __launch_bounds__(256) void k_attn(const u16* __restrict__ Qn, const u16* __restrict__ Kn,
                                              const u16* __restrict__ Vt, const float* __restrict__ temp,
                                              u16* __restrict__ Out) {
  __shared__ __align__(16) u16 Ks[2][64*64];
  __shared__ __align__(16) u16 Vs[2][64*64];
  __shared__ __align__(16) u16 Ps[4*16*64];
  int qg = blockIdx.x, bh = blockIdx.y;
  int b = bh >> 4, h = bh & 15;
  int tid = threadIdx.x, wid = tid >> 6, lane = tid & 63;
  int l15 = lane & 15, l16 = lane >> 4;
  size_t base = (size_t)bh * 2048 * 64;
  size_t vbase = (size_t)bh * 64 * 2048;
  int q0 = qg*64 + wid*16;
  float m2 = fabsf(temp[h]) * 1.44269504f;
  short8 qf[2];
  #pragma unroll
  for (int ks = 0; ks < 2; ks++)
    qf[ks] = *(const short8*)(Qn + base + (size_t)(q0 + l15)*64 + ks*32 + l16*8);
  f32x4 o[4] = {};
  float lrow = 0.f;
  u16* Pw = Ps + wid*16*64;
  uint32_t* Pw32 = (uint32_t*)Pw;

  auto STAGE = [&](int bsel, int kv0) {
    #pragma unroll
    for (int i = 0; i < 2; i++) {
      int base_row = wid*16 + i*8;
      int row = base_row + (lane >> 3);
      int gslot = (lane & 7) ^ (row & 7);
      gload16(Kn + base + (size_t)(kv0 + row)*64 + gslot*8, &Ks[bsel][base_row*64]);
      gload16(Vt + vbase + (size_t)row*2048 + kv0 + gslot*8, &Vs[bsel][base_row*64]);
    }
  };

  STAGE(0, 0);
  __syncthreads();
  int cur = 0;
  for (int kv0 = 0; kv0 < 2048; kv0 += 64) {
    if (kv0 + 64 < 2048) STAGE(cur ^ 1, kv0 + 64);
    f32x4 s[4] = {};
    #pragma unroll
    for (int ks = 0; ks < 2; ks++) {
      short8 kf[4];
      #pragma unroll
      for (int nt = 0; nt < 4; nt++) {
        int row = nt*16 + l15;
        kf[nt] = *(const short8*)&Ks[cur][row*64 + (((ks*4 + l16) ^ (row&7))*8)];
      }
      #pragma unroll
      for (int nt = 0; nt < 4; nt++)
        s[nt] = __builtin_amdgcn_mfma_f32_16x16x32_bf16(kf[nt], qf[ks], s[nt], 0, 0, 0);
    }
    float tsum = 0.f;
    #pragma unroll
    for (int nt = 0; nt < 4; nt++) {
      #pragma unroll
      for (int rp = 0; rp < 2; rp++) {
        float p0 = fast_exp2(s[nt][2*rp]   - m2);
        float p1 = fast_exp2(s[nt][2*rp+1] - m2);
        tsum += p0 + p1;
        uint32_t pk;
        asm("v_cvt_pk_bf16_f32 %0, %1, %2" : "=v"(pk) : "v"(p0), "v"(p1));
        int w = nt*8 + l16*2 + rp;
        int slot = w >> 2;
        Pw32[l15*32 + ((slot ^ (l15 & 7))*4) + (w & 3)] = pk;
      }
    }
    lrow += tsum;
    asm volatile("s_waitcnt lgkmcnt(0)" ::: "memory");
    __builtin_amdgcn_sched_barrier(0);
    #pragma unroll
    for (int ks = 0; ks < 2; ks++) {
      short8 pf = *(const short8*)&Pw[l15*64 + (((ks*4 + l16) ^ (l15&7))*8)];
      short8 vf[4];
      #pragma unroll
      for (int dt = 0; dt < 4; dt++) {
        int row = dt*16 + l15;
        vf[dt] = *(const short8*)&Vs[cur][row*64 + (((ks*4 + l16) ^ (row&7))*8)];
      }
      #pragma unroll
      for (int dt = 0; dt < 4; dt++)
        o[dt] = __builtin_amdgcn_mfma_f32_16x16x32_bf16(vf[dt], pf, o[dt], 0, 0, 0);
    }
    __syncthreads();
    cur ^= 1;
  }
  lrow += __shfl_xor(lrow, 16);
  lrow += __shfl_xor(lrow, 32);
  float rl = 1.0f / lrow;
  int tok = b*2048 + q0 + l15;
  #pragma unroll
  for (int dt = 0; dt < 4; dt++) {
    u16x4 ov;
    #pragma unroll
    for (int r = 0; r < 4; r++) ov[r] = f2bf(o[dt][r] * rl);
    *(u16x4*)(Out + (size_t)tok*1024 + h*64 + dt*16 + l16*4) = ov;
  }
}

// ---------------- workspace layout (bytes) ----------------
static constexpr size_t OFF_WQKV  = 0;                         // 3072*1024*2
static constexpr size_t OFF_WPROJ = OFF_WQKV  + 6291456;       // 1024*1024*2
static constexpr size_t OFF_W1    = OFF_WPROJ + 2097152;       // 4096*1024*2
static constexpr size_t OFF_W2    = OFF_W1    + 8388608;       // 1024*4096*2
static constexpr size_t OFF_HBF   = OFF_W2    + 8388608;       // 4096*1024*2
static constexpr size_t OFF_H2BF  = OFF_HBF   + 8388608;
static constexpr size_t OFF_QKVBF = OFF_H2BF  + 8388608;       // 4096*3072*2
static constexpr size_t OFF_QN    = OFF_QKVBF + 25165824;      // 32*2048*64*2
static constexpr size_t OFF_KN    = OFF_QN    + 8388608;
static constexpr size_t OFF_VT    = OFF_KN    + 8388608;
static constexpr size_t OFF_AOUT  = OFF_VT    + 8388608;
static constexpr size_t OFF_X1    = OFF_AOUT  + 8388608;       // 4096*1024*4
static constexpr size_t OFF_HID   = OFF_X1    + 16777216;      // 4096*4096*2 (32MB)
// proj partials (32MB): OFF_HID region (hid not yet written during proj)
// mlp2 partials (32MB): OFF_QN..OFF_X1 (QN/KN/VT/AOUT all dead after proj)

extern "C" void kernel_launch(void* const* d_in, const int* in_sizes, int n_in,
                              void* d_out, int out_size, void* d_ws, size_t ws_size,
                              hipStream_t stream) {
  (void)in_sizes; (void)n_in; (void)out_size; (void)ws_size;
  const float* x     = (const float*)d_in[0];
  const float* ln1g  = (const float*)d_in[1];
  const float* ln1b  = (const float*)d_in[2];
  const float* wqkv  = (const float*)d_in[3];
  const float* wproj = (const float*)d_in[4];
  const float* temp  = (const float*)d_in[5];
  const float* ln2g  = (const float*)d_in[6];
  const float* ln2b  = (const float*)d_in[7];
  const float* w1    = (const float*)d_in[8];
  const float* b1    = (const float*)d_in[9];
  const float* w2    = (const float*)d_in[10];
  const float* b2    = (const float*)d_in[11];

  char* ws = (char*)d_ws;
  u16* wqkv_bf  = (u16*)(ws + OFF_WQKV);
  u16* wproj_bf = (u16*)(ws + OFF_WPROJ);
  u16* w1_bf    = (u16*)(ws + OFF_W1);
  u16* w2_bf    = (u16*)(ws + OFF_W2);
  u16* h_bf     = (u16*)(ws + OFF_HBF);
  u16* h2_bf    = (u16*)(ws + OFF_H2BF);
  u16* qkv_bf   = (u16*)(ws + OFF_QKVBF);
  u16* Qn       = (u16*)(ws + OFF_QN);
  u16* Kn       = (u16*)(ws + OFF_KN);
  u16* Vt       = (u16*)(ws + OFF_VT);
  u16* aout_bf  = (u16*)(ws + OFF_AOUT);
  float* x1     = (float*)(ws + OFF_X1);
  u16* hid_bf   = (u16*)(ws + OFF_HID);
  u16* part_p   = (u16*)(ws + OFF_HID);   // proj partials
  u16* part_m   = (u16*)(ws + OFF_QN);    // mlp2 partials
  float* outf   = (float*)d_out;

  // allow 96KB dynamic LDS on the 256^2 GEMM (host-side attr set, capture-safe)
  static bool attr_done = false;
  if (!attr_done) {
    hipFuncSetAttribute((const void*)k_g256<2>, hipFuncAttributeMaxDynamicSharedMemorySize, 98304);
    hipFuncSetAttribute((const void*)k_g256<4>, hipFuncAttributeMaxDynamicSharedMemorySize, 98304);
    hipFuncSetAttribute((const void*)k_g256<6>, hipFuncAttributeMaxDynamicSharedMemorySize, 98304);
    attr_done = true;
  }

  k_cvt<<<3072, 256, 0, stream>>>(wqkv,  wqkv_bf,  786432);
  k_cvt<<<1024, 256, 0, stream>>>(wproj, wproj_bf, 262144);
  k_cvt<<<4096, 256, 0, stream>>>(w1,    w1_bf,    1048576);
  k_cvt<<<4096, 256, 0, stream>>>(w2,    w2_bf,    1048576);

  k_ln<<<4096, 256, 0, stream>>>(x, ln1g, ln1b, h_bf);
  // qkv = h @ w_qkv^T -> bf16 [4096,3072]
  k_g256<4><<<dim3(12, 16), 512, 98304, stream>>>(h_bf, wqkv_bf, nullptr, qkv_bf, 4096, 3072, 1024, 1024);
  k_prep<<<dim3(32, 32), 256, 0, stream>>>(qkv_bf, temp, Qn, Kn, Vt);
  k_attn<<<dim3(32, 32), 256, 0, stream>>>(Qn, Kn, Vt, temp, aout_bf);
  // proj split-K=4 partials -> x1 = x + sum(P)
  k_g256<6><<<dim3(4, 16, 4), 512, 98304, stream>>>(aout_bf, wproj_bf, nullptr, part_p, 4096, 1024, 1024, 256);
  k_red4<0><<<4096, 256, 0, stream>>>(x, nullptr, part_p, x1);
  k_ln<<<4096, 256, 0, stream>>>(x1, ln2g, ln2b, h2_bf);
  // mlp1: hid = gelu(h2 @ w1^T + b1) -> bf16 [4096,4096]
  k_g256<2><<<dim3(16, 16), 512, 98304, stream>>>(h2_bf, w1_bf, b1, hid_bf, 4096, 4096, 1024, 1024);
  // mlp2 split-K=4 partials -> out = x1 + b2 + sum(Q)
  k_g256<6><<<dim3(4, 16, 4), 512, 98304, stream>>>(hid_bf, w2_bf, nullptr, part_m, 4096, 1024, 4096, 1024);
  k_red4<1><<<4096, 256, 0, stream>>>(x1, b2, part_m, outf);
}

// Round 6
// 260.789 us; speedup vs baseline: 1.0931x; 1.0297x over previous
//
#include <hip/hip_runtime.h>
#include <cstdint>
#include <cstddef>

typedef unsigned short u16;
typedef __attribute__((ext_vector_type(8))) short short8;
typedef __attribute__((ext_vector_type(4))) float f32x4;
typedef __attribute__((ext_vector_type(4))) float float4v;
typedef __attribute__((ext_vector_type(4))) u16 u16x4;

__device__ __forceinline__ u16 f2bf(float f) {
  union { float f; uint32_t u; } v; v.f = f;
  uint32_t u = v.u;
  return (u16)((u + 0x7FFFu + ((u >> 16) & 1u)) >> 16);
}
__device__ __forceinline__ float bf2f(u16 s) {
  union { uint32_t u; float f; } v; v.u = ((uint32_t)s) << 16; return v.f;
}

__device__ __forceinline__ float fast_exp2(float x) {
#if __has_builtin(__builtin_amdgcn_exp2f)
  return __builtin_amdgcn_exp2f(x);
#else
  return exp2f(x);
#endif
}

// async global->LDS, 16B per lane, dest = wave-uniform base + lane*16
__device__ __forceinline__ void gload16(const u16* g, u16* l) {
  __builtin_amdgcn_global_load_lds((const __attribute__((address_space(1))) void*)g,
                                   (__attribute__((address_space(3))) void*)l,
                                   16, 0, 0);
}

// ---------------- convert f32 -> bf16 ----------------
__global__ __launch_bounds__(256) void k_cvt(const float* __restrict__ in, u16* __restrict__ out, int n4) {
  int i = blockIdx.x * 256 + threadIdx.x;
  if (i >= n4) return;
  float4v v = *(const float4v*)(in + (size_t)i * 4);
  u16x4 o;
  #pragma unroll
  for (int j = 0; j < 4; j++) o[j] = f2bf(v[j]);
  *(u16x4*)(out + (size_t)i * 4) = o;
}

// ---------------- layernorm f32 -> bf16 (one block per row of 1024) ----------------
__global__ __launch_bounds__(256) void k_ln(const float* __restrict__ x, const float* __restrict__ g,
                                            const float* __restrict__ b, u16* __restrict__ out) {
  int row = blockIdx.x, tid = threadIdx.x;
  int wid = tid >> 6;
  const float* xr = x + (size_t)row * 1024;
  float4v v = *(const float4v*)(xr + tid * 4);
  float s = v[0] + v[1] + v[2] + v[3];
  float sq = v[0]*v[0] + v[1]*v[1] + v[2]*v[2] + v[3]*v[3];
  #pragma unroll
  for (int m = 1; m <= 32; m <<= 1) { s += __shfl_xor(s, m); sq += __shfl_xor(sq, m); }
  __shared__ float ss[4], ssq[4];
  if ((tid & 63) == 0) { ss[wid] = s; ssq[wid] = sq; }
  __syncthreads();
  s = ss[0] + ss[1] + ss[2] + ss[3];
  sq = ssq[0] + ssq[1] + ssq[2] + ssq[3];
  float mu = s * (1.0f/1024.0f);
  float var = sq * (1.0f/1024.0f) - mu*mu;
  float rs = rsqrtf(var + 1e-5f);
  u16x4 o;
  #pragma unroll
  for (int j = 0; j < 4; j++) {
    float y = (v[j] - mu) * rs * g[tid*4+j] + b[tid*4+j];
    o[j] = f2bf(y);
  }
  *(u16x4*)(out + (size_t)row * 1024 + tid * 4) = o;
}

// ---------------- fused: x1 = x + sum4(P); h2 = LN(x1)*g+b  (one row/block) ----------------
__global__ __launch_bounds__(256) void k_redln(const float* __restrict__ x, const u16* __restrict__ P,
                                               const float* __restrict__ g, const float* __restrict__ b,
                                               float* __restrict__ x1, u16* __restrict__ h2) {
  int row = blockIdx.x, tid = threadIdx.x;
  int wid = tid >> 6;
  size_t off = (size_t)row * 1024 + tid * 4;
  float4v v = *(const float4v*)(x + off);
  #pragma unroll
  for (int z = 0; z < 4; z++) {
    u16x4 p = *(const u16x4*)(P + (size_t)z * 4194304 + off);
    #pragma unroll
    for (int j = 0; j < 4; j++) v[j] += bf2f(p[j]);
  }
  *(float4v*)(x1 + off) = v;
  float s = v[0] + v[1] + v[2] + v[3];
  float sq = v[0]*v[0] + v[1]*v[1] + v[2]*v[2] + v[3]*v[3];
  #pragma unroll
  for (int m = 1; m <= 32; m <<= 1) { s += __shfl_xor(s, m); sq += __shfl_xor(sq, m); }
  __shared__ float ss[4], ssq[4];
  if ((tid & 63) == 0) { ss[wid] = s; ssq[wid] = sq; }
  __syncthreads();
  s = ss[0] + ss[1] + ss[2] + ss[3];
  sq = ssq[0] + ssq[1] + ssq[2] + ssq[3];
  float mu = s * (1.0f/1024.0f);
  float var = sq * (1.0f/1024.0f) - mu*mu;
  float rs = rsqrtf(var + 1e-5f);
  u16x4 o;
  #pragma unroll
  for (int j = 0; j < 4; j++) o[j] = f2bf((v[j] - mu) * rs * g[tid*4+j] + b[tid*4+j]);
  *(u16x4*)(h2 + off) = o;
}

// ================= 256x256 GEMM, BK=32, 3-deep counted-vmcnt pipeline =================
// EPI: 2=bf16 gelu(acc+bias), 4=bf16 plain, 6=bf16 partial at z*M*N
template<int EPI>
__global__ __launch_bounds__(512, 2) void k_g256(const u16* __restrict__ A, const u16* __restrict__ B,
                                                 const float* __restrict__ bias, u16* __restrict__ Cb,
                                                 int M, int N, int K, int Ksub) {
  extern __shared__ __align__(16) u16 smem[];   // [3][2][8192]
  int tid = threadIdx.x;
  int gx = gridDim.x;
  int lin = blockIdx.y * gx + blockIdx.x;
  int nwg = gx * gridDim.y;
  int cpx = nwg >> 3;
  int swz = (lin & 7) * cpx + (lin >> 3);
  int bx = swz % gx, by = swz / gx;
  int m0 = by * 256, n0 = bx * 256;
  int kbase = blockIdx.z * Ksub;
  int wid = tid >> 6, lane = tid & 63;
  int wm = wid >> 2, wn = wid & 3;          // 2x4 waves; wave tile 128x64
  int l15 = lane & 15, l16 = lane >> 4;

  f32x4 acc[8][4] = {};
  int nt = Ksub >> 5;

  auto STAGE = [&](int bsel, int kb) {
    u16* abase = smem + bsel * 16384;
    u16* bbase = abase + 8192;
    #pragma unroll
    for (int i = 0; i < 2; i++) {
      int c = i*512 + tid;
      int R = c >> 3, p = c & 7;
      int sp = p ^ (R & 7);
      int r = 2*R + (sp >> 2);
      int g = sp & 3;
      gload16(A + (size_t)(m0 + r)*K + kb + g*8, abase + c*8);
      gload16(B + (size_t)(n0 + r)*K + kb + g*8, bbase + c*8);
    }
  };

  STAGE(0, kbase);
  STAGE(1, kbase + 32);

  for (int t = 0; t < nt; ++t) {
    if (t + 1 < nt) asm volatile("s_waitcnt vmcnt(4)" ::: "memory");
    else            asm volatile("s_waitcnt vmcnt(0)" ::: "memory");
    __builtin_amdgcn_sched_barrier(0);
    __builtin_amdgcn_s_barrier();
    __builtin_amdgcn_sched_barrier(0);
    if (t + 2 < nt) STAGE((t + 2) % 3, kbase + (t + 2) * 32);
    const u16* ab = smem + (t % 3) * 16384;
    const u16* bb = ab + 8192;
    short8 af[8], bf[4];
    #pragma unroll
    for (int mf = 0; mf < 8; mf++) {
      int r = wm*128 + mf*16 + l15;
      int R = r >> 1;
      int sp = ((r & 1)*4 + l16) ^ (R & 7);
      af[mf] = *(const short8*)(ab + R*64 + sp*8);
    }
    #pragma unroll
    for (int nf = 0; nf < 4; nf++) {
      int r = wn*64 + nf*16 + l15;
      int R = r >> 1;
      int sp = ((r & 1)*4 + l16) ^ (R & 7);
      bf[nf] = *(const short8*)(bb + R*64 + sp*8);
    }
    asm volatile("s_waitcnt lgkmcnt(0)" ::: "memory");
    __builtin_amdgcn_sched_barrier(0);
    __builtin_amdgcn_s_setprio(1);
    #pragma unroll
    for (int mf = 0; mf < 8; mf++)
      #pragma unroll
      for (int nf = 0; nf < 4; nf++)
        acc[mf][nf] = __builtin_amdgcn_mfma_f32_16x16x32_bf16(af[mf], bf[nf], acc[mf][nf], 0, 0, 0);
    __builtin_amdgcn_s_setprio(0);
  }

  size_t zoff = (EPI == 6) ? (size_t)blockIdx.z * M * N : 0;
  #pragma unroll
  for (int mf = 0; mf < 8; mf++) {
    #pragma unroll
    for (int nf = 0; nf < 4; nf++) {
      int col = n0 + wn*64 + nf*16 + l15;
      #pragma unroll
      for (int r = 0; r < 4; r++) {
        int row = m0 + wm*128 + mf*16 + l16*4 + r;
        float v = acc[mf][nf][r];
        if constexpr (EPI == 2) { v += bias[col]; v = 0.5f*v*(1.0f + erff(v*0.70710678118f)); }
        Cb[zoff + (size_t)row*N + col] = f2bf(v);
      }
    }
  }
}

// ---------------- reduce: out = base (+bias) + P0+P1+P2+P3 ----------------
template<int HASB>
__global__ __launch_bounds__(256) void k_red4(const float* __restrict__ base, const float* __restrict__ bias,
                                              const u16* __restrict__ P, float* __restrict__ out) {
  int i = blockIdx.x * 256 + threadIdx.x;
  float4v v = *(const float4v*)(base + (size_t)i * 4);
  if constexpr (HASB) {
    float4v bb = *(const float4v*)(bias + (size_t)(i & 255) * 4);
    #pragma unroll
    for (int j = 0; j < 4; j++) v[j] += bb[j];
  }
  #pragma unroll
  for (int z = 0; z < 4; z++) {
    u16x4 p = *(const u16x4*)(P + (size_t)z * 4194304 + (size_t)i * 4);
    #pragma unroll
    for (int j = 0; j < 4; j++) v[j] += bf2f(p[j]);
  }
  *(float4v*)(out + (size_t)i * 4) = v;
}

// ---------------- prep: l2norm q,k (fold temp*log2e into q), V -> V^T ----------------
__global__ __launch_bounds__(256) void k_prep(const u16* __restrict__ qkv, const float* __restrict__ temp,
                                              u16* __restrict__ Qn, u16* __restrict__ Kn, u16* __restrict__ Vt) {
  int grp = blockIdx.x, bh = blockIdx.y;
  int b = bh >> 4, h = bh & 15;
  int tid = threadIdx.x, wid = tid >> 6, lane = tid & 63;
  int n0 = grp * 64;
  __shared__ __align__(16) u16 vs[64*64];
  float tmp = temp[h] * 1.44269504f;
  for (int j = 0; j < 16; j++) {
    int tl = wid + 4*j;
    size_t roff = (size_t)((b*2048) + n0 + tl) * 3072;
    float q = bf2f(qkv[roff + h*64 + lane]);
    float k = bf2f(qkv[roff + 1024 + h*64 + lane]);
    u16 vraw = qkv[roff + 2048 + h*64 + lane];
    float sq = q*q, sk = k*k;
    #pragma unroll
    for (int m = 1; m <= 32; m <<= 1) { sq += __shfl_xor(sq, m); sk += __shfl_xor(sk, m); }
    float qs = tmp / fmaxf(sqrtf(sq), 1e-12f);
    float ksc = 1.0f / fmaxf(sqrtf(sk), 1e-12f);
    size_t obase = ((size_t)bh*2048 + n0 + tl)*64 + lane;
    Qn[obase] = f2bf(q * qs);
    Kn[obase] = f2bf(k * ksc);
    vs[tl*64 + lane] = vraw;
  }
  __syncthreads();
  int d = tid & 63, chunk = tid >> 6;
  u16 vals[16];
  #pragma unroll
  for (int jj = 0; jj < 16; jj++) vals[jj] = vs[(chunk*16 + jj)*64 + d];
  short8 w0, w1v;
  #pragma unroll
  for (int j = 0; j < 8; j++) { w0[j] = (short)vals[j]; w1v[j] = (short)vals[8+j]; }
  size_t vo = ((size_t)bh*64 + d)*2048 + n0 + chunk*16;
  *(short8*)(Vt + vo) = w0;
  *(short8*)(Vt + vo + 8) = w1v;
}

// ---------------- flash attention: 32 q/wave, 128 q/block, fixed-max softmax ----------------
// XCD-clustered: each XCD owns 4 bh (K/V stay L2-resident per XCD).
__global__ __launch_bounds__(256) void k_attn(const u16* __restrict__ Qn, const u16* __restrict__ Kn,
                                              const u16* __restrict__ Vt, const float* __restrict__ temp,
                                              u16* __restrict__ Out) {
  __shared__ __align__(16) u16 Ks[2][64*64];
  __shared__ __align__(16) u16 Vs[2][64*64];
  __shared__ __align__(16) u16 Ps[4*2*16*64];   // [wave][g][16q][64kv]
  // grid = 512 linear blocks; XCD c (=lin&7) -> bh {4c..4c+3}, qg 0..15
  int lin = blockIdx.y * gridDim.x + blockIdx.x;
  int c = lin & 7, t5 = lin >> 3;
  int bh = c*4 + (t5 >> 4);
  int qg = t5 & 15;
  int b = bh >> 4, h = bh & 15;
  int tid = threadIdx.x, wid = tid >> 6, lane = tid & 63;
  int l15 = lane & 15, l16 = lane >> 4;
  size_t base = (size_t)bh * 2048 * 64;
  size_t vbase = (size_t)bh * 64 * 2048;
  int q0 = qg*128 + wid*32;
  float m2 = fabsf(temp[h]) * 1.44269504f;
  short8 qf[2][2];
  #pragma unroll
  for (int g = 0; g < 2; g++)
    #pragma unroll
    for (int ks = 0; ks < 2; ks++)
      qf[g][ks] = *(const short8*)(Qn + base + (size_t)(q0 + g*16 + l15)*64 + ks*32 + l16*8);
  f32x4 o[2][4] = {};
  float lrow[2] = {0.f, 0.f};
  u16* Pw = Ps + wid*2048;
  uint32_t* Pw32 = (uint32_t*)Pw;

  auto STAGE = [&](int bsel, int kv0) {
    #pragma unroll
    for (int i = 0; i < 2; i++) {
      int base_row = wid*16 + i*8;
      int row = base_row + (lane >> 3);
      int gslot = (lane & 7) ^ (row & 7);
      gload16(Kn + base + (size_t)(kv0 + row)*64 + gslot*8, &Ks[bsel][base_row*64]);
      gload16(Vt + vbase + (size_t)row*2048 + kv0 + gslot*8, &Vs[bsel][base_row*64]);
    }
  };

  STAGE(0, 0);
  __syncthreads();
  int cur = 0;
  for (int kv0 = 0; kv0 < 2048; kv0 += 64) {
    if (kv0 + 64 < 2048) STAGE(cur ^ 1, kv0 + 64);
    // S^T = K . Q^T for both 16-q groups (kf shared)
    f32x4 s[2][4] = {};
    #pragma unroll
    for (int ks = 0; ks < 2; ks++) {
      short8 kf[4];
      #pragma unroll
      for (int nt = 0; nt < 4; nt++) {
        int row = nt*16 + l15;
        kf[nt] = *(const short8*)&Ks[cur][row*64 + (((ks*4 + l16) ^ (row&7))*8)];
      }
      #pragma unroll
      for (int nt = 0; nt < 4; nt++) {
        s[0][nt] = __builtin_amdgcn_mfma_f32_16x16x32_bf16(kf[nt], qf[0][ks], s[0][nt], 0, 0, 0);
        s[1][nt] = __builtin_amdgcn_mfma_f32_16x16x32_bf16(kf[nt], qf[1][ks], s[1][nt], 0, 0, 0);
      }
    }
    // fixed-max softmax (p = exp2(s - m2)), pack pairs -> P^T in LDS per group
    #pragma unroll
    for (int g = 0; g < 2; g++) {
      float tsum = 0.f;
      #pragma unroll
      for (int nt = 0; nt < 4; nt++) {
        #pragma unroll
        for (int rp = 0; rp < 2; rp++) {
          float p0 = fast_exp2(s[g][nt][2*rp]   - m2);
          float p1 = fast_exp2(s[g][nt][2*rp+1] - m2);
          tsum += p0 + p1;
          uint32_t pk;
          asm("v_cvt_pk_bf16_f32 %0, %1, %2" : "=v"(pk) : "v"(p0), "v"(p1));
          int w = nt*8 + l16*2 + rp;
          int slot = w >> 2;
          Pw32[g*512 + l15*32 + ((slot ^ (l15 & 7))*4) + (w & 3)] = pk;
        }
      }
      lrow[g] += tsum;
    }
    asm volatile("s_waitcnt lgkmcnt(0)" ::: "memory");
    __builtin_amdgcn_sched_barrier(0);
    // O^T += V^T . P^T (vf shared across groups)
    #pragma unroll
    for (int ks = 0; ks < 2; ks++) {
      short8 vf[4];
      #pragma unroll
      for (int dt = 0; dt < 4; dt++) {
        int row = dt*16 + l15;
        vf[dt] = *(const short8*)&Vs[cur][row*64 + (((ks*4 + l16) ^ (row&7))*8)];
      }
      short8 pf0 = *(const short8*)&Pw[0*1024 + l15*64 + (((ks*4 + l16) ^ (l15&7))*8)];
      short8 pf1 = *(const short8*)&Pw[1*1024 + l15*64 + (((ks*4 + l16) ^ (l15&7))*8)];
      #pragma unroll
      for (int dt = 0; dt < 4; dt++) {
        o[0][dt] = __builtin_amdgcn_mfma_f32_16x16x32_bf16(vf[dt], pf0, o[0][dt], 0, 0, 0);
        o[1][dt] = __builtin_amdgcn_mfma_f32_16x16x32_bf16(vf[dt], pf1, o[1][dt], 0, 0, 0);
      }
    }
    __syncthreads();
    cur ^= 1;
  }
  #pragma unroll
  for (int g = 0; g < 2; g++) {
    float l = lrow[g];
    l += __shfl_xor(l, 16);
    l += __shfl_xor(l, 32);
    float rl = 1.0f / l;
    int tok = b*2048 + q0 + g*16 + l15;
    #pragma unroll
    for (int dt = 0; dt < 4; dt++) {
      u16x4 ov;
      #pragma unroll
      for (int r = 0; r < 4; r++) ov[r] = f2bf(o[g][dt][r] * rl);
      *(u16x4*)(Out + (size_t)tok*1024 + h*64 + dt*16 + l16*4) = ov;
    }
  }
}

// ---------------- workspace layout (bytes) ----------------
static constexpr size_t OFF_WQKV  = 0;
static constexpr size_t OFF_WPROJ = OFF_WQKV  + 6291456;
static constexpr size_t OFF_W1    = OFF_WPROJ + 2097152;
static constexpr size_t OFF_W2    = OFF_W1    + 8388608;
static constexpr size_t OFF_HBF   = OFF_W2    + 8388608;
static constexpr size_t OFF_H2BF  = OFF_HBF   + 8388608;
static constexpr size_t OFF_QKVBF = OFF_H2BF  + 8388608;
static constexpr size_t OFF_QN    = OFF_QKVBF + 25165824;
static constexpr size_t OFF_KN    = OFF_QN    + 8388608;
static constexpr size_t OFF_VT    = OFF_KN    + 8388608;
static constexpr size_t OFF_AOUT  = OFF_VT    + 8388608;
static constexpr size_t OFF_X1    = OFF_AOUT  + 8388608;
static constexpr size_t OFF_HID   = OFF_X1    + 16777216;

extern "C" void kernel_launch(void* const* d_in, const int* in_sizes, int n_in,
                              void* d_out, int out_size, void* d_ws, size_t ws_size,
                              hipStream_t stream) {
  (void)in_sizes; (void)n_in; (void)out_size; (void)ws_size;
  const float* x     = (const float*)d_in[0];
  const float* ln1g  = (const float*)d_in[1];
  const float* ln1b  = (const float*)d_in[2];
  const float* wqkv  = (const float*)d_in[3];
  const float* wproj = (const float*)d_in[4];
  const float* temp  = (const float*)d_in[5];
  const float* ln2g  = (const float*)d_in[6];
  const float* ln2b  = (const float*)d_in[7];
  const float* w1    = (const float*)d_in[8];
  const float* b1    = (const float*)d_in[9];
  const float* w2    = (const float*)d_in[10];
  const float* b2    = (const float*)d_in[11];

  char* ws = (char*)d_ws;
  u16* wqkv_bf  = (u16*)(ws + OFF_WQKV);
  u16* wproj_bf = (u16*)(ws + OFF_WPROJ);
  u16* w1_bf    = (u16*)(ws + OFF_W1);
  u16* w2_bf    = (u16*)(ws + OFF_W2);
  u16* h_bf     = (u16*)(ws + OFF_HBF);
  u16* h2_bf    = (u16*)(ws + OFF_H2BF);
  u16* qkv_bf   = (u16*)(ws + OFF_QKVBF);
  u16* Qn       = (u16*)(ws + OFF_QN);
  u16* Kn       = (u16*)(ws + OFF_KN);
  u16* Vt       = (u16*)(ws + OFF_VT);
  u16* aout_bf  = (u16*)(ws + OFF_AOUT);
  float* x1     = (float*)(ws + OFF_X1);
  u16* hid_bf   = (u16*)(ws + OFF_HID);
  u16* part_p   = (u16*)(ws + OFF_HID);   // proj partials (hid dead here)
  u16* part_m   = (u16*)(ws + OFF_QN);    // mlp2 partials (QN..AOUT dead here)
  float* outf   = (float*)d_out;

  static bool attr_done = false;
  if (!attr_done) {
    hipFuncSetAttribute((const void*)k_g256<2>, hipFuncAttributeMaxDynamicSharedMemorySize, 98304);
    hipFuncSetAttribute((const void*)k_g256<4>, hipFuncAttributeMaxDynamicSharedMemorySize, 98304);
    hipFuncSetAttribute((const void*)k_g256<6>, hipFuncAttributeMaxDynamicSharedMemorySize, 98304);
    attr_done = true;
  }

  k_cvt<<<3072, 256, 0, stream>>>(wqkv,  wqkv_bf,  786432);
  k_cvt<<<1024, 256, 0, stream>>>(wproj, wproj_bf, 262144);
  k_cvt<<<4096, 256, 0, stream>>>(w1,    w1_bf,    1048576);
  k_cvt<<<4096, 256, 0, stream>>>(w2,    w2_bf,    1048576);

  k_ln<<<4096, 256, 0, stream>>>(x, ln1g, ln1b, h_bf);
  k_g256<4><<<dim3(12, 16), 512, 98304, stream>>>(h_bf, wqkv_bf, nullptr, qkv_bf, 4096, 3072, 1024, 1024);
  k_prep<<<dim3(32, 32), 256, 0, stream>>>(qkv_bf, temp, Qn, Kn, Vt);
  k_attn<<<dim3(16, 32), 256, 0, stream>>>(Qn, Kn, Vt, temp, aout_bf);
  // proj split-K=4 partials -> fused reduce + LN2
  k_g256<6><<<dim3(4, 16, 4), 512, 98304, stream>>>(aout_bf, wproj_bf, nullptr, part_p, 4096, 1024, 1024, 256);
  k_redln<<<4096, 256, 0, stream>>>(x, part_p, ln2g, ln2b, x1, h2_bf);
  // mlp1: hid = gelu(h2 @ w1^T + b1)
  k_g256<2><<<dim3(16, 16), 512, 98304, stream>>>(h2_bf, w1_bf, b1, hid_bf, 4096, 4096, 1024, 1024);
  // mlp2 split-K=4 partials -> out = x1 + b2 + sum(Q)
  k_g256<6><<<dim3(4, 16, 4), 512, 98304, stream>>>(hid_bf, w2_bf, nullptr, part_m, 4096, 1024, 4096, 1024);
  k_red4<1><<<4096, 256, 0, stream>>>(x1, b2, part_m, outf);
}

// Round 7
// 252.981 us; speedup vs baseline: 1.1269x; 1.0309x over previous
//
#include <hip/hip_runtime.h>
#include <cstdint>
#include <cstddef>

typedef unsigned short u16;
typedef __attribute__((ext_vector_type(8))) short short8;
typedef __attribute__((ext_vector_type(4))) float f32x4;
typedef __attribute__((ext_vector_type(4))) float float4v;
typedef __attribute__((ext_vector_type(4))) u16 u16x4;

__device__ __forceinline__ u16 f2bf(float f) {
  union { float f; uint32_t u; } v; v.f = f;
  uint32_t u = v.u;
  return (u16)((u + 0x7FFFu + ((u >> 16) & 1u)) >> 16);
}
__device__ __forceinline__ float bf2f(u16 s) {
  union { uint32_t u; float f; } v; v.u = ((uint32_t)s) << 16; return v.f;
}

__device__ __forceinline__ float fast_exp2(float x) {
#if __has_builtin(__builtin_amdgcn_exp2f)
  return __builtin_amdgcn_exp2f(x);
#else
  return exp2f(x);
#endif
}

// async global->LDS, 16B per lane, dest = wave-uniform base + lane*16
__device__ __forceinline__ void gload16(const u16* g, u16* l) {
  __builtin_amdgcn_global_load_lds((const __attribute__((address_space(1))) void*)g,
                                   (__attribute__((address_space(3))) void*)l,
                                   16, 0, 0);
}

// ---------------- convert f32 -> bf16 ----------------
__global__ __launch_bounds__(256) void k_cvt(const float* __restrict__ in, u16* __restrict__ out, int n4) {
  int i = blockIdx.x * 256 + threadIdx.x;
  if (i >= n4) return;
  float4v v = *(const float4v*)(in + (size_t)i * 4);
  u16x4 o;
  #pragma unroll
  for (int j = 0; j < 4; j++) o[j] = f2bf(v[j]);
  *(u16x4*)(out + (size_t)i * 4) = o;
}

// ---------------- layernorm f32 -> bf16 (one block per row of 1024) ----------------
__global__ __launch_bounds__(256) void k_ln(const float* __restrict__ x, const float* __restrict__ g,
                                            const float* __restrict__ b, u16* __restrict__ out) {
  int row = blockIdx.x, tid = threadIdx.x;
  int wid = tid >> 6;
  const float* xr = x + (size_t)row * 1024;
  float4v v = *(const float4v*)(xr + tid * 4);
  float s = v[0] + v[1] + v[2] + v[3];
  float sq = v[0]*v[0] + v[1]*v[1] + v[2]*v[2] + v[3]*v[3];
  #pragma unroll
  for (int m = 1; m <= 32; m <<= 1) { s += __shfl_xor(s, m); sq += __shfl_xor(sq, m); }
  __shared__ float ss[4], ssq[4];
  if ((tid & 63) == 0) { ss[wid] = s; ssq[wid] = sq; }
  __syncthreads();
  s = ss[0] + ss[1] + ss[2] + ss[3];
  sq = ssq[0] + ssq[1] + ssq[2] + ssq[3];
  float mu = s * (1.0f/1024.0f);
  float var = sq * (1.0f/1024.0f) - mu*mu;
  float rs = rsqrtf(var + 1e-5f);
  u16x4 o;
  #pragma unroll
  for (int j = 0; j < 4; j++) {
    float y = (v[j] - mu) * rs * g[tid*4+j] + b[tid*4+j];
    o[j] = f2bf(y);
  }
  *(u16x4*)(out + (size_t)row * 1024 + tid * 4) = o;
}

// ---------------- fused: x1 = x + sum4(P); h2 = LN(x1)*g+b  (one row/block) ----------------
__global__ __launch_bounds__(256) void k_redln(const float* __restrict__ x, const u16* __restrict__ P,
                                               const float* __restrict__ g, const float* __restrict__ b,
                                               float* __restrict__ x1, u16* __restrict__ h2) {
  int row = blockIdx.x, tid = threadIdx.x;
  int wid = tid >> 6;
  size_t off = (size_t)row * 1024 + tid * 4;
  float4v v = *(const float4v*)(x + off);
  #pragma unroll
  for (int z = 0; z < 4; z++) {
    u16x4 p = *(const u16x4*)(P + (size_t)z * 4194304 + off);
    #pragma unroll
    for (int j = 0; j < 4; j++) v[j] += bf2f(p[j]);
  }
  *(float4v*)(x1 + off) = v;
  float s = v[0] + v[1] + v[2] + v[3];
  float sq = v[0]*v[0] + v[1]*v[1] + v[2]*v[2] + v[3]*v[3];
  #pragma unroll
  for (int m = 1; m <= 32; m <<= 1) { s += __shfl_xor(s, m); sq += __shfl_xor(sq, m); }
  __shared__ float ss[4], ssq[4];
  if ((tid & 63) == 0) { ss[wid] = s; ssq[wid] = sq; }
  __syncthreads();
  s = ss[0] + ss[1] + ss[2] + ss[3];
  sq = ssq[0] + ssq[1] + ssq[2] + ssq[3];
  float mu = s * (1.0f/1024.0f);
  float var = sq * (1.0f/1024.0f) - mu*mu;
  float rs = rsqrtf(var + 1e-5f);
  u16x4 o;
  #pragma unroll
  for (int j = 0; j < 4; j++) o[j] = f2bf((v[j] - mu) * rs * g[tid*4+j] + b[tid*4+j]);
  *(u16x4*)(h2 + off) = o;
}

// ================= 256x256 GEMM, BK=32, 3-deep counted-vmcnt pipeline =================
// EPI: 2=bf16 gelu(acc+bias), 4=bf16 plain, 6=bf16 partial at z*M*N
template<int EPI>
__global__ __launch_bounds__(512, 2) void k_g256(const u16* __restrict__ A, const u16* __restrict__ B,
                                                 const float* __restrict__ bias, u16* __restrict__ Cb,
                                                 int M, int N, int K, int Ksub) {
  extern __shared__ __align__(16) u16 smem[];   // [3][2][8192]
  int tid = threadIdx.x;
  int gx = gridDim.x;
  int lin = blockIdx.y * gx + blockIdx.x;
  int nwg = gx * gridDim.y;
  int cpx = nwg >> 3;
  int swz = (lin & 7) * cpx + (lin >> 3);
  int bx = swz % gx, by = swz / gx;
  int m0 = by * 256, n0 = bx * 256;
  int kbase = blockIdx.z * Ksub;
  int wid = tid >> 6, lane = tid & 63;
  int wm = wid >> 2, wn = wid & 3;          // 2x4 waves; wave tile 128x64
  int l15 = lane & 15, l16 = lane >> 4;

  f32x4 acc[8][4] = {};
  int nt = Ksub >> 5;

  auto STAGE = [&](int bsel, int kb) {
    u16* abase = smem + bsel * 16384;
    u16* bbase = abase + 8192;
    #pragma unroll
    for (int i = 0; i < 2; i++) {
      int c = i*512 + tid;
      int R = c >> 3, p = c & 7;
      int sp = p ^ (R & 7);
      int r = 2*R + (sp >> 2);
      int g = sp & 3;
      gload16(A + (size_t)(m0 + r)*K + kb + g*8, abase + c*8);
      gload16(B + (size_t)(n0 + r)*K + kb + g*8, bbase + c*8);
    }
  };

  STAGE(0, kbase);
  STAGE(1, kbase + 32);

  for (int t = 0; t < nt; ++t) {
    if (t + 1 < nt) asm volatile("s_waitcnt vmcnt(4)" ::: "memory");
    else            asm volatile("s_waitcnt vmcnt(0)" ::: "memory");
    __builtin_amdgcn_sched_barrier(0);
    __builtin_amdgcn_s_barrier();
    __builtin_amdgcn_sched_barrier(0);
    if (t + 2 < nt) STAGE((t + 2) % 3, kbase + (t + 2) * 32);
    const u16* ab = smem + (t % 3) * 16384;
    const u16* bb = ab + 8192;
    short8 af[8], bf[4];
    #pragma unroll
    for (int mf = 0; mf < 8; mf++) {
      int r = wm*128 + mf*16 + l15;
      int R = r >> 1;
      int sp = ((r & 1)*4 + l16) ^ (R & 7);
      af[mf] = *(const short8*)(ab + R*64 + sp*8);
    }
    #pragma unroll
    for (int nf = 0; nf < 4; nf++) {
      int r = wn*64 + nf*16 + l15;
      int R = r >> 1;
      int sp = ((r & 1)*4 + l16) ^ (R & 7);
      bf[nf] = *(const short8*)(bb + R*64 + sp*8);
    }
    asm volatile("s_waitcnt lgkmcnt(0)" ::: "memory");
    __builtin_amdgcn_sched_barrier(0);
    __builtin_amdgcn_s_setprio(1);
    #pragma unroll
    for (int mf = 0; mf < 8; mf++)
      #pragma unroll
      for (int nf = 0; nf < 4; nf++)
        acc[mf][nf] = __builtin_amdgcn_mfma_f32_16x16x32_bf16(af[mf], bf[nf], acc[mf][nf], 0, 0, 0);
    __builtin_amdgcn_s_setprio(0);
  }

  size_t zoff = (EPI == 6) ? (size_t)blockIdx.z * M * N : 0;
  #pragma unroll
  for (int mf = 0; mf < 8; mf++) {
    #pragma unroll
    for (int nf = 0; nf < 4; nf++) {
      int col = n0 + wn*64 + nf*16 + l15;
      #pragma unroll
      for (int r = 0; r < 4; r++) {
        int row = m0 + wm*128 + mf*16 + l16*4 + r;
        float v = acc[mf][nf][r];
        if constexpr (EPI == 2) { v += bias[col]; v = 0.5f*v*(1.0f + erff(v*0.70710678118f)); }
        Cb[zoff + (size_t)row*N + col] = f2bf(v);
      }
    }
  }
}

// ---------------- reduce: out = base (+bias) + P0+P1+P2+P3 ----------------
template<int HASB>
__global__ __launch_bounds__(256) void k_red4(const float* __restrict__ base, const float* __restrict__ bias,
                                              const u16* __restrict__ P, float* __restrict__ out) {
  int i = blockIdx.x * 256 + threadIdx.x;
  float4v v = *(const float4v*)(base + (size_t)i * 4);
  if constexpr (HASB) {
    float4v bb = *(const float4v*)(bias + (size_t)(i & 255) * 4);
    #pragma unroll
    for (int j = 0; j < 4; j++) v[j] += bb[j];
  }
  #pragma unroll
  for (int z = 0; z < 4; z++) {
    u16x4 p = *(const u16x4*)(P + (size_t)z * 4194304 + (size_t)i * 4);
    #pragma unroll
    for (int j = 0; j < 4; j++) v[j] += bf2f(p[j]);
  }
  *(float4v*)(out + (size_t)i * 4) = v;
}

// ---------------- prep: l2norm q,k (fold temp*log2e into q), V -> V^T ----------------
__global__ __launch_bounds__(256) void k_prep(const u16* __restrict__ qkv, const float* __restrict__ temp,
                                              u16* __restrict__ Qn, u16* __restrict__ Kn, u16* __restrict__ Vt) {
  int grp = blockIdx.x, bh = blockIdx.y;
  int b = bh >> 4, h = bh & 15;
  int tid = threadIdx.x, wid = tid >> 6, lane = tid & 63;
  int n0 = grp * 64;
  __shared__ __align__(16) u16 vs[64*64];
  float tmp = temp[h] * 1.44269504f;
  for (int j = 0; j < 16; j++) {
    int tl = wid + 4*j;
    size_t roff = (size_t)((b*2048) + n0 + tl) * 3072;
    float q = bf2f(qkv[roff + h*64 + lane]);
    float k = bf2f(qkv[roff + 1024 + h*64 + lane]);
    u16 vraw = qkv[roff + 2048 + h*64 + lane];
    float sq = q*q, sk = k*k;
    #pragma unroll
    for (int m = 1; m <= 32; m <<= 1) { sq += __shfl_xor(sq, m); sk += __shfl_xor(sk, m); }
    float qs = tmp / fmaxf(sqrtf(sq), 1e-12f);
    float ksc = 1.0f / fmaxf(sqrtf(sk), 1e-12f);
    size_t obase = ((size_t)bh*2048 + n0 + tl)*64 + lane;
    Qn[obase] = f2bf(q * qs);
    Kn[obase] = f2bf(k * ksc);
    vs[tl*64 + lane] = vraw;
  }
  __syncthreads();
  int d = tid & 63, chunk = tid >> 6;
  u16 vals[16];
  #pragma unroll
  for (int jj = 0; jj < 16; jj++) vals[jj] = vs[(chunk*16 + jj)*64 + d];
  short8 w0, w1v;
  #pragma unroll
  for (int j = 0; j < 8; j++) { w0[j] = (short)vals[j]; w1v[j] = (short)vals[8+j]; }
  size_t vo = ((size_t)bh*64 + d)*2048 + n0 + chunk*16;
  *(short8*)(Vt + vo) = w0;
  *(short8*)(Vt + vo + 8) = w1v;
}

// ---------------- flash attention v3: permuted-K QK^T, P stays in registers ----------------
// 32 q/wave (2 groups of 16), 128 q/block, fixed-max softmax (|q.k|<=1), XCD-clustered.
// QK^T A-operand rows fed permuted (row = base + (l15&3) + 8*(l15>>2), bases {0,4}+32*kvs)
// so the S/P registers land exactly in the PV B-fragment layout (k = l16*8+j).
// No P LDS, no bank conflicts, no mid-tile drain.
// LDS swizzle key = bits {r0,r1,r3} of row -> 2-way (free) for both K and V reads.
__device__ __forceinline__ int akey(int row) { return (row & 3) | (((row >> 3) & 1) << 2); }

__global__ __launch_bounds__(256) void k_attn(const u16* __restrict__ Qn, const u16* __restrict__ Kn,
                                              const u16* __restrict__ Vt, const float* __restrict__ temp,
                                              u16* __restrict__ Out) {
  __shared__ __align__(16) u16 Ks[2][64*64];
  __shared__ __align__(16) u16 Vs[2][64*64];
  int lin = blockIdx.y * gridDim.x + blockIdx.x;
  int c = lin & 7, t5 = lin >> 3;
  int bh = c*4 + (t5 >> 4);
  int qg = t5 & 15;
  int b = bh >> 4, h = bh & 15;
  int tid = threadIdx.x, wid = tid >> 6, lane = tid & 63;
  int l15 = lane & 15, l16 = lane >> 4;
  size_t base = (size_t)bh * 2048 * 64;
  size_t vbase = (size_t)bh * 64 * 2048;
  int q0 = qg*128 + wid*32;
  float m2 = fabsf(temp[h]) * 1.44269504f;
  short8 qf[2][2];
  #pragma unroll
  for (int g = 0; g < 2; g++)
    #pragma unroll
    for (int ks = 0; ks < 2; ks++)
      qf[g][ks] = *(const short8*)(Qn + base + (size_t)(q0 + g*16 + l15)*64 + ks*32 + l16*8);
  f32x4 o[2][4] = {};
  float lrow[2] = {0.f, 0.f};
  // permuted K-row index for QK^T A-operand (per 16-row set)
  int prow = (l15 & 3) + 8*(l15 >> 2);

  auto STAGE = [&](int bsel, int kv0) {
    #pragma unroll
    for (int i = 0; i < 2; i++) {
      int cc = i*256 + tid;                 // 512 chunks = 64 rows x 8 slots
      int row = cc >> 3, p = cc & 7;
      int g = p ^ akey(row);
      gload16(Kn + base + (size_t)(kv0 + row)*64 + g*8, &Ks[bsel][(i*256 + wid*64)*8]);
      gload16(Vt + vbase + (size_t)row*2048 + kv0 + g*8, &Vs[bsel][(i*256 + wid*64)*8]);
    }
  };

  STAGE(0, 0);
  __syncthreads();
  int cur = 0;
  for (int kv0 = 0; kv0 < 2048; kv0 += 64) {
    if (kv0 + 64 < 2048) STAGE(cur ^ 1, kv0 + 64);
    // QK^T: s[g][set], set = kvs*2 + ab; row base = ab*4 + kvs*32
    f32x4 s[2][4] = {};
    #pragma unroll
    for (int dks = 0; dks < 2; dks++) {
      #pragma unroll
      for (int ss = 0; ss < 4; ss++) {
        int row = (ss & 1)*4 + (ss >> 1)*32 + prow;
        short8 kf = *(const short8*)&Ks[cur][row*64 + ((dks*4 + l16) ^ akey(row))*8];
        s[0][ss] = __builtin_amdgcn_mfma_f32_16x16x32_bf16(kf, qf[0][dks], s[0][ss], 0, 0, 0);
        s[1][ss] = __builtin_amdgcn_mfma_f32_16x16x32_bf16(kf, qf[1][dks], s[1][ss], 0, 0, 0);
      }
    }
    // softmax: p = exp2(s - m2); pack straight into PV B-fragments (registers only)
    short8 pf[2][2];
    #pragma unroll
    for (int g = 0; g < 2; g++) {
      float tsum = 0.f;
      #pragma unroll
      for (int kvs = 0; kvs < 2; kvs++) {
        float e[8];
        #pragma unroll
        for (int r = 0; r < 4; r++) {
          e[r]   = fast_exp2(s[g][kvs*2][r]   - m2);
          e[4+r] = fast_exp2(s[g][kvs*2+1][r] - m2);
        }
        #pragma unroll
        for (int r = 0; r < 8; r++) tsum += e[r];
        union { uint32_t u[4]; short8 v; } pu;
        #pragma unroll
        for (int w = 0; w < 4; w++) {
          uint32_t pk;
          asm("v_cvt_pk_bf16_f32 %0, %1, %2" : "=v"(pk) : "v"(e[2*w]), "v"(e[2*w+1]));
          pu.u[w] = pk;
        }
        pf[g][kvs] = pu.v;
      }
      lrow[g] += tsum;
    }
    // PV: O^T += V^T . P  (vf shared across groups)
    #pragma unroll
    for (int kvs = 0; kvs < 2; kvs++) {
      short8 vf[4];
      #pragma unroll
      for (int dt = 0; dt < 4; dt++) {
        int row = dt*16 + l15;
        vf[dt] = *(const short8*)&Vs[cur][row*64 + (((kvs*4 + l16) ^ akey(row))*8)];
      }
      #pragma unroll
      for (int dt = 0; dt < 4; dt++) {
        o[0][dt] = __builtin_amdgcn_mfma_f32_16x16x32_bf16(vf[dt], pf[0][kvs], o[0][dt], 0, 0, 0);
        o[1][dt] = __builtin_amdgcn_mfma_f32_16x16x32_bf16(vf[dt], pf[1][kvs], o[1][dt], 0, 0, 0);
      }
    }
    __syncthreads();
    cur ^= 1;
  }
  #pragma unroll
  for (int g = 0; g < 2; g++) {
    float l = lrow[g];
    l += __shfl_xor(l, 16);
    l += __shfl_xor(l, 32);
    float rl = 1.0f / l;
    int tok = b*2048 + q0 + g*16 + l15;
    #pragma unroll
    for (int dt = 0; dt < 4; dt++) {
      u16x4 ov;
      #pragma unroll
      for (int r = 0; r < 4; r++) ov[r] = f2bf(o[g][dt][r] * rl);
      *(u16x4*)(Out + (size_t)tok*1024 + h*64 + dt*16 + l16*4) = ov;
    }
  }
}

// ---------------- workspace layout (bytes) ----------------
static constexpr size_t OFF_WQKV  = 0;
static constexpr size_t OFF_WPROJ = OFF_WQKV  + 6291456;
static constexpr size_t OFF_W1    = OFF_WPROJ + 2097152;
static constexpr size_t OFF_W2    = OFF_W1    + 8388608;
static constexpr size_t OFF_HBF   = OFF_W2    + 8388608;
static constexpr size_t OFF_H2BF  = OFF_HBF   + 8388608;
static constexpr size_t OFF_QKVBF = OFF_H2BF  + 8388608;
static constexpr size_t OFF_QN    = OFF_QKVBF + 25165824;
static constexpr size_t OFF_KN    = OFF_QN    + 8388608;
static constexpr size_t OFF_VT    = OFF_KN    + 8388608;
static constexpr size_t OFF_AOUT  = OFF_VT    + 8388608;
static constexpr size_t OFF_X1    = OFF_AOUT  + 8388608;
static constexpr size_t OFF_HID   = OFF_X1    + 16777216;

extern "C" void kernel_launch(void* const* d_in, const int* in_sizes, int n_in,
                              void* d_out, int out_size, void* d_ws, size_t ws_size,
                              hipStream_t stream) {
  (void)in_sizes; (void)n_in; (void)out_size; (void)ws_size;
  const float* x     = (const float*)d_in[0];
  const float* ln1g  = (const float*)d_in[1];
  const float* ln1b  = (const float*)d_in[2];
  const float* wqkv  = (const float*)d_in[3];
  const float* wproj = (const float*)d_in[4];
  const float* temp  = (const float*)d_in[5];
  const float* ln2g  = (const float*)d_in[6];
  const float* ln2b  = (const float*)d_in[7];
  const float* w1    = (const float*)d_in[8];
  const float* b1    = (const float*)d_in[9];
  const float* w2    = (const float*)d_in[10];
  const float* b2    = (const float*)d_in[11];

  char* ws = (char*)d_ws;
  u16* wqkv_bf  = (u16*)(ws + OFF_WQKV);
  u16* wproj_bf = (u16*)(ws + OFF_WPROJ);
  u16* w1_bf    = (u16*)(ws + OFF_W1);
  u16* w2_bf    = (u16*)(ws + OFF_W2);
  u16* h_bf     = (u16*)(ws + OFF_HBF);
  u16* h2_bf    = (u16*)(ws + OFF_H2BF);
  u16* qkv_bf   = (u16*)(ws + OFF_QKVBF);
  u16* Qn       = (u16*)(ws + OFF_QN);
  u16* Kn       = (u16*)(ws + OFF_KN);
  u16* Vt       = (u16*)(ws + OFF_VT);
  u16* aout_bf  = (u16*)(ws + OFF_AOUT);
  float* x1     = (float*)(ws + OFF_X1);
  u16* hid_bf   = (u16*)(ws + OFF_HID);
  u16* part_p   = (u16*)(ws + OFF_HID);   // proj partials (hid dead here)
  u16* part_m   = (u16*)(ws + OFF_QN);    // mlp2 partials (QN..AOUT dead here)
  float* outf   = (float*)d_out;

  static bool attr_done = false;
  if (!attr_done) {
    hipFuncSetAttribute((const void*)k_g256<2>, hipFuncAttributeMaxDynamicSharedMemorySize, 98304);
    hipFuncSetAttribute((const void*)k_g256<4>, hipFuncAttributeMaxDynamicSharedMemorySize, 98304);
    hipFuncSetAttribute((const void*)k_g256<6>, hipFuncAttributeMaxDynamicSharedMemorySize, 98304);
    attr_done = true;
  }

  k_cvt<<<3072, 256, 0, stream>>>(wqkv,  wqkv_bf,  786432);
  k_cvt<<<1024, 256, 0, stream>>>(wproj, wproj_bf, 262144);
  k_cvt<<<4096, 256, 0, stream>>>(w1,    w1_bf,    1048576);
  k_cvt<<<4096, 256, 0, stream>>>(w2,    w2_bf,    1048576);

  k_ln<<<4096, 256, 0, stream>>>(x, ln1g, ln1b, h_bf);
  k_g256<4><<<dim3(12, 16), 512, 98304, stream>>>(h_bf, wqkv_bf, nullptr, qkv_bf, 4096, 3072, 1024, 1024);
  k_prep<<<dim3(32, 32), 256, 0, stream>>>(qkv_bf, temp, Qn, Kn, Vt);
  k_attn<<<dim3(16, 32), 256, 0, stream>>>(Qn, Kn, Vt, temp, aout_bf);
  // proj split-K=4 partials -> fused reduce + LN2
  k_g256<6><<<dim3(4, 16, 4), 512, 98304, stream>>>(aout_bf, wproj_bf, nullptr, part_p, 4096, 1024, 1024, 256);
  k_redln<<<4096, 256, 0, stream>>>(x, part_p, ln2g, ln2b, x1, h2_bf);
  // mlp1: hid = gelu(h2 @ w1^T + b1)
  k_g256<2><<<dim3(16, 16), 512, 98304, stream>>>(h2_bf, w1_bf, b1, hid_bf, 4096, 4096, 1024, 1024);
  // mlp2 split-K=4 partials -> out = x1 + b2 + sum(Q)
  k_g256<6><<<dim3(4, 16, 4), 512, 98304, stream>>>(hid_bf, w2_bf, nullptr, part_m, 4096, 1024, 4096, 1024);
  k_red4<1><<<4096, 256, 0, stream>>>(x1, b2, part_m, outf);
}

// Round 10
// 250.567 us; speedup vs baseline: 1.1377x; 1.0096x over previous
//
#include <hip/hip_runtime.h>
#include <cstdint>
#include <cstddef>

typedef unsigned short u16;
typedef __attribute__((ext_vector_type(8))) short short8;
typedef __attribute__((ext_vector_type(4))) float f32x4;
typedef __attribute__((ext_vector_type(4))) float float4v;
typedef __attribute__((ext_vector_type(4))) u16 u16x4;

__device__ __forceinline__ u16 f2bf(float f) {
  union { float f; uint32_t u; } v; v.f = f;
  uint32_t u = v.u;
  return (u16)((u + 0x7FFFu + ((u >> 16) & 1u)) >> 16);
}
__device__ __forceinline__ float bf2f(u16 s) {
  union { uint32_t u; float f; } v; v.u = ((uint32_t)s) << 16; return v.f;
}

__device__ __forceinline__ float fast_exp2(float x) {
#if __has_builtin(__builtin_amdgcn_exp2f)
  return __builtin_amdgcn_exp2f(x);
#else
  return exp2f(x);
#endif
}

// async global->LDS, 16B per lane, dest = wave-uniform base + lane*16
__device__ __forceinline__ void gload16(const u16* g, u16* l) {
  __builtin_amdgcn_global_load_lds((const __attribute__((address_space(1))) void*)g,
                                   (__attribute__((address_space(3))) void*)l,
                                   16, 0, 0);
}

// ---------------- convert f32 -> bf16 ----------------
__global__ __launch_bounds__(256) void k_cvt(const float* __restrict__ in, u16* __restrict__ out, int n4) {
  int i = blockIdx.x * 256 + threadIdx.x;
  if (i >= n4) return;
  float4v v = *(const float4v*)(in + (size_t)i * 4);
  u16x4 o;
  #pragma unroll
  for (int j = 0; j < 4; j++) o[j] = f2bf(v[j]);
  *(u16x4*)(out + (size_t)i * 4) = o;
}

// ---------------- layernorm f32 -> bf16 (one block per row of 1024) ----------------
__global__ __launch_bounds__(256) void k_ln(const float* __restrict__ x, const float* __restrict__ g,
                                            const float* __restrict__ b, u16* __restrict__ out) {
  int row = blockIdx.x, tid = threadIdx.x;
  int wid = tid >> 6;
  const float* xr = x + (size_t)row * 1024;
  float4v v = *(const float4v*)(xr + tid * 4);
  float s = v[0] + v[1] + v[2] + v[3];
  float sq = v[0]*v[0] + v[1]*v[1] + v[2]*v[2] + v[3]*v[3];
  #pragma unroll
  for (int m = 1; m <= 32; m <<= 1) { s += __shfl_xor(s, m); sq += __shfl_xor(sq, m); }
  __shared__ float ss[4], ssq[4];
  if ((tid & 63) == 0) { ss[wid] = s; ssq[wid] = sq; }
  __syncthreads();
  s = ss[0] + ss[1] + ss[2] + ss[3];
  sq = ssq[0] + ssq[1] + ssq[2] + ssq[3];
  float mu = s * (1.0f/1024.0f);
  float var = sq * (1.0f/1024.0f) - mu*mu;
  float rs = rsqrtf(var + 1e-5f);
  u16x4 o;
  #pragma unroll
  for (int j = 0; j < 4; j++) {
    float y = (v[j] - mu) * rs * g[tid*4+j] + b[tid*4+j];
    o[j] = f2bf(y);
  }
  *(u16x4*)(out + (size_t)row * 1024 + tid * 4) = o;
}

// ---------------- fused: x1 = x + sum4(P); h2 = LN(x1)*g+b  (one row/block) ----------------
__global__ __launch_bounds__(256) void k_redln(const float* __restrict__ x, const u16* __restrict__ P,
                                               const float* __restrict__ g, const float* __restrict__ b,
                                               float* __restrict__ x1, u16* __restrict__ h2) {
  int row = blockIdx.x, tid = threadIdx.x;
  int wid = tid >> 6;
  size_t off = (size_t)row * 1024 + tid * 4;
  float4v v = *(const float4v*)(x + off);
  #pragma unroll
  for (int z = 0; z < 4; z++) {
    u16x4 p = *(const u16x4*)(P + (size_t)z * 4194304 + off);
    #pragma unroll
    for (int j = 0; j < 4; j++) v[j] += bf2f(p[j]);
  }
  *(float4v*)(x1 + off) = v;
  float s = v[0] + v[1] + v[2] + v[3];
  float sq = v[0]*v[0] + v[1]*v[1] + v[2]*v[2] + v[3]*v[3];
  #pragma unroll
  for (int m = 1; m <= 32; m <<= 1) { s += __shfl_xor(s, m); sq += __shfl_xor(sq, m); }
  __shared__ float ss[4], ssq[4];
  if ((tid & 63) == 0) { ss[wid] = s; ssq[wid] = sq; }
  __syncthreads();
  s = ss[0] + ss[1] + ss[2] + ss[3];
  sq = ssq[0] + ssq[1] + ssq[2] + ssq[3];
  float mu = s * (1.0f/1024.0f);
  float var = sq * (1.0f/1024.0f) - mu*mu;
  float rs = rsqrtf(var + 1e-5f);
  u16x4 o;
  #pragma unroll
  for (int j = 0; j < 4; j++) o[j] = f2bf((v[j] - mu) * rs * g[tid*4+j] + b[tid*4+j]);
  *(u16x4*)(h2 + off) = o;
}

// ================= 256x256 GEMM, BK=32, 2-slot (64KB) pipeline -> 2 blocks/CU =================
// Slot invariant: tile t in slot t&1. Per iter (derived, all-builtin vmcnt window):
//   vmcnt(0): tile t landed (wave-local; issued one full iteration earlier, latency hidden)
//   s_barrier: all waves' tile-t stores visible; all reads of tile t-1 complete
//   STAGE(t+1) into slot (t+1)&1 (= t-1's slot, now free)
//   12 ds_read frags(t) -> lgkmcnt(0) -> 32 MFMA (setprio)
// Cross-block TLP (2 blocks/CU) overlaps one block's ds_reads with the other's MFMAs.
// EPI: 2=bf16 gelu(acc+bias), 4=bf16 plain, 6=bf16 partial at z*M*N
template<int EPI>
__global__ __launch_bounds__(512, 2) void k_g256(const u16* __restrict__ A, const u16* __restrict__ B,
                                                 const float* __restrict__ bias, u16* __restrict__ Cb,
                                                 int M, int N, int K, int Ksub) {
  extern __shared__ __align__(16) u16 smem[];   // [2][2][8192] u16 = 64KB
  int tid = threadIdx.x;
  int gx = gridDim.x;
  int lin = blockIdx.y * gx + blockIdx.x;
  int nwg = gx * gridDim.y;
  int cpx = nwg >> 3;
  int swz = (lin & 7) * cpx + (lin >> 3);
  int bx = swz % gx, by = swz / gx;
  int m0 = by * 256, n0 = bx * 256;
  int kbase = blockIdx.z * Ksub;
  int wid = tid >> 6, lane = tid & 63;
  int wm = wid >> 2, wn = wid & 3;          // 2x4 waves; wave tile 128(M) x 64(N)
  int l15 = lane & 15, l16 = lane >> 4;

  f32x4 acc[8][4] = {};
  int nt = Ksub >> 5;

  auto STAGE = [&](int bsel, int kb) {
    u16* abase = smem + bsel * 16384;
    u16* bbase = abase + 8192;
    #pragma unroll
    for (int i = 0; i < 2; i++) {
      int c = i*512 + tid;
      int R = c >> 3, p = c & 7;
      int sp = p ^ (R & 7);
      int r = 2*R + (sp >> 2);
      int g = sp & 3;
      gload16(A + (size_t)(m0 + r)*K + kb + g*8, abase + c*8);
      gload16(B + (size_t)(n0 + r)*K + kb + g*8, bbase + c*8);
    }
  };

  STAGE(0, kbase);                          // tile 0 in flight (4 gload_lds)

  for (int t = 0; t < nt; ++t) {
    int sl = t & 1;
    asm volatile("s_waitcnt vmcnt(0)" ::: "memory");   // tile t landed (wave-local)
    __builtin_amdgcn_sched_barrier(0);
    __builtin_amdgcn_s_barrier();           // all waves: tile t visible, t-1 reads done
    __builtin_amdgcn_sched_barrier(0);
    if (t + 1 < nt) STAGE(sl ^ 1, kbase + (t + 1) * 32);  // in flight across this tile's compute
    const u16* ab = smem + sl * 16384;
    const u16* bb = ab + 8192;
    short8 af[8], bf[4];
    #pragma unroll
    for (int mf = 0; mf < 8; mf++) {
      int r = wm*128 + mf*16 + l15;
      int R = r >> 1;
      int sp = ((r & 1)*4 + l16) ^ (R & 7);
      af[mf] = *(const short8*)(ab + R*64 + sp*8);
    }
    #pragma unroll
    for (int nf = 0; nf < 4; nf++) {
      int r = wn*64 + nf*16 + l15;
      int R = r >> 1;
      int sp = ((r & 1)*4 + l16) ^ (R & 7);
      bf[nf] = *(const short8*)(bb + R*64 + sp*8);
    }
    asm volatile("s_waitcnt lgkmcnt(0)" ::: "memory");
    __builtin_amdgcn_sched_barrier(0);
    __builtin_amdgcn_s_setprio(1);
    #pragma unroll
    for (int mf = 0; mf < 8; mf++)
      #pragma unroll
      for (int nf = 0; nf < 4; nf++)
        acc[mf][nf] = __builtin_amdgcn_mfma_f32_16x16x32_bf16(af[mf], bf[nf], acc[mf][nf], 0, 0, 0);
    __builtin_amdgcn_s_setprio(0);
  }

  size_t zoff = (EPI == 6) ? (size_t)blockIdx.z * M * N : 0;
  #pragma unroll
  for (int mf = 0; mf < 8; mf++) {
    #pragma unroll
    for (int nf = 0; nf < 4; nf++) {
      int col = n0 + wn*64 + nf*16 + l15;
      #pragma unroll
      for (int r = 0; r < 4; r++) {
        int row = m0 + wm*128 + mf*16 + l16*4 + r;
        float v = acc[mf][nf][r];
        if constexpr (EPI == 2) { v += bias[col]; v = 0.5f*v*(1.0f + erff(v*0.70710678118f)); }
        Cb[zoff + (size_t)row*N + col] = f2bf(v);
      }
    }
  }
}

// ---------------- reduce: out = base (+bias) + P0+P1+P2+P3 ----------------
template<int HASB>
__global__ __launch_bounds__(256) void k_red4(const float* __restrict__ base, const float* __restrict__ bias,
                                              const u16* __restrict__ P, float* __restrict__ out) {
  int i = blockIdx.x * 256 + threadIdx.x;
  float4v v = *(const float4v*)(base + (size_t)i * 4);
  if constexpr (HASB) {
    float4v bb = *(const float4v*)(bias + (size_t)(i & 255) * 4);
    #pragma unroll
    for (int j = 0; j < 4; j++) v[j] += bb[j];
  }
  #pragma unroll
  for (int z = 0; z < 4; z++) {
    u16x4 p = *(const u16x4*)(P + (size_t)z * 4194304 + (size_t)i * 4);
    #pragma unroll
    for (int j = 0; j < 4; j++) v[j] += bf2f(p[j]);
  }
  *(float4v*)(out + (size_t)i * 4) = v;
}

// ---------------- prep: l2norm q,k (fold temp*log2e into q), V -> V^T ----------------
__global__ __launch_bounds__(256) void k_prep(const u16* __restrict__ qkv, const float* __restrict__ temp,
                                              u16* __restrict__ Qn, u16* __restrict__ Kn, u16* __restrict__ Vt) {
  int grp = blockIdx.x, bh = blockIdx.y;
  int b = bh >> 4, h = bh & 15;
  int tid = threadIdx.x, wid = tid >> 6, lane = tid & 63;
  int n0 = grp * 64;
  __shared__ __align__(16) u16 vs[64*64];
  float tmp = temp[h] * 1.44269504f;
  for (int j = 0; j < 16; j++) {
    int tl = wid + 4*j;
    size_t roff = (size_t)((b*2048) + n0 + tl) * 3072;
    float q = bf2f(qkv[roff + h*64 + lane]);
    float k = bf2f(qkv[roff + 1024 + h*64 + lane]);
    u16 vraw = qkv[roff + 2048 + h*64 + lane];
    float sq = q*q, sk = k*k;
    #pragma unroll
    for (int m = 1; m <= 32; m <<= 1) { sq += __shfl_xor(sq, m); sk += __shfl_xor(sk, m); }
    float qs = tmp / fmaxf(sqrtf(sq), 1e-12f);
    float ksc = 1.0f / fmaxf(sqrtf(sk), 1e-12f);
    size_t obase = ((size_t)bh*2048 + n0 + tl)*64 + lane;
    Qn[obase] = f2bf(q * qs);
    Kn[obase] = f2bf(k * ksc);
    vs[tl*64 + lane] = vraw;
  }
  __syncthreads();
  int d = tid & 63, chunk = tid >> 6;
  u16 vals[16];
  #pragma unroll
  for (int jj = 0; jj < 16; jj++) vals[jj] = vs[(chunk*16 + jj)*64 + d];
  short8 w0, w1v;
  #pragma unroll
  for (int j = 0; j < 8; j++) { w0[j] = (short)vals[j]; w1v[j] = (short)vals[8+j]; }
  size_t vo = ((size_t)bh*64 + d)*2048 + n0 + chunk*16;
  *(short8*)(Vt + vo) = w0;
  *(short8*)(Vt + vo + 8) = w1v;
}

// ---------------- flash attention v3: permuted-K QK^T, P stays in registers ----------------
__device__ __forceinline__ int akey(int row) { return (row & 3) | (((row >> 3) & 1) << 2); }

__global__ __launch_bounds__(256) void k_attn(const u16* __restrict__ Qn, const u16* __restrict__ Kn,
                                              const u16* __restrict__ Vt, const float* __restrict__ temp,
                                              u16* __restrict__ Out) {
  __shared__ __align__(16) u16 Ks[2][64*64];
  __shared__ __align__(16) u16 Vs[2][64*64];
  int lin = blockIdx.y * gridDim.x + blockIdx.x;
  int c = lin & 7, t5 = lin >> 3;
  int bh = c*4 + (t5 >> 4);
  int qg = t5 & 15;
  int b = bh >> 4, h = bh & 15;
  int tid = threadIdx.x, wid = tid >> 6, lane = tid & 63;
  int l15 = lane & 15, l16 = lane >> 4;
  size_t base = (size_t)bh * 2048 * 64;
  size_t vbase = (size_t)bh * 64 * 2048;
  int q0 = qg*128 + wid*32;
  float m2 = fabsf(temp[h]) * 1.44269504f;
  short8 qf[2][2];
  #pragma unroll
  for (int g = 0; g < 2; g++)
    #pragma unroll
    for (int ks = 0; ks < 2; ks++)
      qf[g][ks] = *(const short8*)(Qn + base + (size_t)(q0 + g*16 + l15)*64 + ks*32 + l16*8);
  f32x4 o[2][4] = {};
  float lrow[2] = {0.f, 0.f};
  int prow = (l15 & 3) + 8*(l15 >> 2);

  auto STAGE = [&](int bsel, int kv0) {
    #pragma unroll
    for (int i = 0; i < 2; i++) {
      int cc = i*256 + tid;
      int row = cc >> 3, p = cc & 7;
      int g = p ^ akey(row);
      gload16(Kn + base + (size_t)(kv0 + row)*64 + g*8, &Ks[bsel][(i*256 + wid*64)*8]);
      gload16(Vt + vbase + (size_t)row*2048 + kv0 + g*8, &Vs[bsel][(i*256 + wid*64)*8]);
    }
  };

  STAGE(0, 0);
  __syncthreads();
  int cur = 0;
  for (int kv0 = 0; kv0 < 2048; kv0 += 64) {
    if (kv0 + 64 < 2048) STAGE(cur ^ 1, kv0 + 64);
    f32x4 s[2][4] = {};
    #pragma unroll
    for (int dks = 0; dks < 2; dks++) {
      #pragma unroll
      for (int ss = 0; ss < 4; ss++) {
        int row = (ss & 1)*4 + (ss >> 1)*32 + prow;
        short8 kf = *(const short8*)&Ks[cur][row*64 + ((dks*4 + l16) ^ akey(row))*8];
        s[0][ss] = __builtin_amdgcn_mfma_f32_16x16x32_bf16(kf, qf[0][dks], s[0][ss], 0, 0, 0);
        s[1][ss] = __builtin_amdgcn_mfma_f32_16x16x32_bf16(kf, qf[1][dks], s[1][ss], 0, 0, 0);
      }
    }
    short8 pf[2][2];
    #pragma unroll
    for (int g = 0; g < 2; g++) {
      float tsum = 0.f;
      #pragma unroll
      for (int kvs = 0; kvs < 2; kvs++) {
        float e[8];
        #pragma unroll
        for (int r = 0; r < 4; r++) {
          e[r]   = fast_exp2(s[g][kvs*2][r]   - m2);
          e[4+r] = fast_exp2(s[g][kvs*2+1][r] - m2);
        }
        #pragma unroll
        for (int r = 0; r < 8; r++) tsum += e[r];
        union { uint32_t u[4]; short8 v; } pu;
        #pragma unroll
        for (int w = 0; w < 4; w++) {
          uint32_t pk;
          asm("v_cvt_pk_bf16_f32 %0, %1, %2" : "=v"(pk) : "v"(e[2*w]), "v"(e[2*w+1]));
          pu.u[w] = pk;
        }
        pf[g][kvs] = pu.v;
      }
      lrow[g] += tsum;
    }
    #pragma unroll
    for (int kvs = 0; kvs < 2; kvs++) {
      short8 vf[4];
      #pragma unroll
      for (int dt = 0; dt < 4; dt++) {
        int row = dt*16 + l15;
        vf[dt] = *(const short8*)&Vs[cur][row*64 + (((kvs*4 + l16) ^ akey(row))*8)];
      }
      #pragma unroll
      for (int dt = 0; dt < 4; dt++) {
        o[0][dt] = __builtin_amdgcn_mfma_f32_16x16x32_bf16(vf[dt], pf[0][kvs], o[0][dt], 0, 0, 0);
        o[1][dt] = __builtin_amdgcn_mfma_f32_16x16x32_bf16(vf[dt], pf[1][kvs], o[1][dt], 0, 0, 0);
      }
    }
    __syncthreads();
    cur ^= 1;
  }
  #pragma unroll
  for (int g = 0; g < 2; g++) {
    float l = lrow[g];
    l += __shfl_xor(l, 16);
    l += __shfl_xor(l, 32);
    float rl = 1.0f / l;
    int tok = b*2048 + q0 + g*16 + l15;
    #pragma unroll
    for (int dt = 0; dt < 4; dt++) {
      u16x4 ov;
      #pragma unroll
      for (int r = 0; r < 4; r++) ov[r] = f2bf(o[g][dt][r] * rl);
      *(u16x4*)(Out + (size_t)tok*1024 + h*64 + dt*16 + l16*4) = ov;
    }
  }
}

// ---------------- workspace layout (bytes) ----------------
static constexpr size_t OFF_WQKV  = 0;
static constexpr size_t OFF_WPROJ = OFF_WQKV  + 6291456;
static constexpr size_t OFF_W1    = OFF_WPROJ + 2097152;
static constexpr size_t OFF_W2    = OFF_W1    + 8388608;
static constexpr size_t OFF_HBF   = OFF_W2    + 8388608;
static constexpr size_t OFF_H2BF  = OFF_HBF   + 8388608;
static constexpr size_t OFF_QKVBF = OFF_H2BF  + 8388608;
static constexpr size_t OFF_QN    = OFF_QKVBF + 25165824;
static constexpr size_t OFF_KN    = OFF_QN    + 8388608;
static constexpr size_t OFF_VT    = OFF_KN    + 8388608;
static constexpr size_t OFF_AOUT  = OFF_VT    + 8388608;
static constexpr size_t OFF_X1    = OFF_AOUT  + 8388608;
static constexpr size_t OFF_HID   = OFF_X1    + 16777216;

extern "C" void kernel_launch(void* const* d_in, const int* in_sizes, int n_in,
                              void* d_out, int out_size, void* d_ws, size_t ws_size,
                              hipStream_t stream) {
  (void)in_sizes; (void)n_in; (void)out_size; (void)ws_size;
  const float* x     = (const float*)d_in[0];
  const float* ln1g  = (const float*)d_in[1];
  const float* ln1b  = (const float*)d_in[2];
  const float* wqkv  = (const float*)d_in[3];
  const float* wproj = (const float*)d_in[4];
  const float* temp  = (const float*)d_in[5];
  const float* ln2g  = (const float*)d_in[6];
  const float* ln2b  = (const float*)d_in[7];
  const float* w1    = (const float*)d_in[8];
  const float* b1    = (const float*)d_in[9];
  const float* w2    = (const float*)d_in[10];
  const float* b2    = (const float*)d_in[11];

  char* ws = (char*)d_ws;
  u16* wqkv_bf  = (u16*)(ws + OFF_WQKV);
  u16* wproj_bf = (u16*)(ws + OFF_WPROJ);
  u16* w1_bf    = (u16*)(ws + OFF_W1);
  u16* w2_bf    = (u16*)(ws + OFF_W2);
  u16* h_bf     = (u16*)(ws + OFF_HBF);
  u16* h2_bf    = (u16*)(ws + OFF_H2BF);
  u16* qkv_bf   = (u16*)(ws + OFF_QKVBF);
  u16* Qn       = (u16*)(ws + OFF_QN);
  u16* Kn       = (u16*)(ws + OFF_KN);
  u16* Vt       = (u16*)(ws + OFF_VT);
  u16* aout_bf  = (u16*)(ws + OFF_AOUT);
  float* x1     = (float*)(ws + OFF_X1);
  u16* hid_bf   = (u16*)(ws + OFF_HID);
  u16* part_p   = (u16*)(ws + OFF_HID);   // proj partials (hid dead here)
  u16* part_m   = (u16*)(ws + OFF_QN);    // mlp2 partials (QN..AOUT dead here)
  float* outf   = (float*)d_out;

  static bool attr_done = false;
  if (!attr_done) {
    hipFuncSetAttribute((const void*)k_g256<2>, hipFuncAttributeMaxDynamicSharedMemorySize, 65536);
    hipFuncSetAttribute((const void*)k_g256<4>, hipFuncAttributeMaxDynamicSharedMemorySize, 65536);
    hipFuncSetAttribute((const void*)k_g256<6>, hipFuncAttributeMaxDynamicSharedMemorySize, 65536);
    attr_done = true;
  }

  k_cvt<<<3072, 256, 0, stream>>>(wqkv,  wqkv_bf,  786432);
  k_cvt<<<1024, 256, 0, stream>>>(wproj, wproj_bf, 262144);
  k_cvt<<<4096, 256, 0, stream>>>(w1,    w1_bf,    1048576);
  k_cvt<<<4096, 256, 0, stream>>>(w2,    w2_bf,    1048576);

  k_ln<<<4096, 256, 0, stream>>>(x, ln1g, ln1b, h_bf);
  k_g256<4><<<dim3(12, 16), 512, 65536, stream>>>(h_bf, wqkv_bf, nullptr, qkv_bf, 4096, 3072, 1024, 1024);
  k_prep<<<dim3(32, 32), 256, 0, stream>>>(qkv_bf, temp, Qn, Kn, Vt);
  k_attn<<<dim3(16, 32), 256, 0, stream>>>(Qn, Kn, Vt, temp, aout_bf);
  // proj split-K=4 partials -> fused reduce + LN2
  k_g256<6><<<dim3(4, 16, 4), 512, 65536, stream>>>(aout_bf, wproj_bf, nullptr, part_p, 4096, 1024, 1024, 256);
  k_redln<<<4096, 256, 0, stream>>>(x, part_p, ln2g, ln2b, x1, h2_bf);
  // mlp1: hid = gelu(h2 @ w1^T + b1)
  k_g256<2><<<dim3(16, 16), 512, 65536, stream>>>(h2_bf, w1_bf, b1, hid_bf, 4096, 4096, 1024, 1024);
  // mlp2 split-K=4 partials -> out = x1 + b2 + sum(Q)
  k_g256<6><<<dim3(4, 16, 4), 512, 65536, stream>>>(hid_bf, w2_bf, nullptr, part_m, 4096, 1024, 4096, 1024);
  k_red4<1><<<4096, 256, 0, stream>>>(x1, b2, part_m, outf);
}